// Round 1
// baseline (2295.281 us; speedup 1.0000x reference)
//
#include <hip/hip_runtime.h>

typedef unsigned short u16;
typedef unsigned int   u32;

#define BQ 8
#define NQ 8192
#define MQ 64
#define KQ 3
#define SEGS (BQ*MQ)        /* 512 */
#define MAXCHUNK 3584

/* ---- workspace layout (bytes) ---- */
#define OFF_IDX      (size_t)0         /* int[B*N*3]      786432 */
#define OFF_PERM     (size_t)786432    /* int[196608]     786432 */
#define OFF_CNT      (size_t)1572864   /* int[512]          2048 */
#define OFF_SUMS     (size_t)1574912   /* float[1536]       6144 */
#define OFF_OFFS     (size_t)1581056   /* int[513]     pad  2304 */
#define OFF_CURSOR   (size_t)1583360   /* int[512]          2048 */
#define OFF_NCHUNK   (size_t)1585408   /* int[64]            256 */
#define OFF_CHUNKTAB (size_t)1585664   /* int[2*3584]      28672 */
#define OFF_MEAN     (size_t)1614336   /* float[1536]       6144 */
#define OFF_FALLBACK (size_t)1620480   /* float[8*384]     12288 */
#define OFF_NODEMAX  (size_t)1632768   /* float[512*384]  786432 */
#define OFF_CENTER   (size_t)2419200   /* float[512*3]      6144 */
#define OFF_KNNFEAT  (size_t)2425344   /* float[512*512] 1048576 */
#define OFF_W0T_KNN  (size_t)3473920   /* float[388*512]  794624 */
#define OFF_W1T_KNN  (size_t)4268544   /* float[512*512] 1048576 */
#define OFF_W0T_FIN  (size_t)5317120   /* float[516*768] 1585152 */
#define OFF_W1T_FIN  (size_t)6902272   /* float[768*1024]3145728 */

#define C_BIG_STR 328   /* bf16 elems; 328*2=656B -> lane stride = 4 banks mod 32 (8-phase b128 ok) */
#define C_H1_STR  136

__device__ __forceinline__ u16 f2bf(float f) {
  u32 u = __float_as_uint(f);
  u32 r = (u + 0x7fffu + ((u >> 16) & 1u)) >> 16;  /* RNE */
  return (u16)r;
}
__device__ __forceinline__ u32 pk2(float lo, float hi) {
  return (u32)f2bf(lo) | ((u32)f2bf(hi) << 16);
}
__device__ __forceinline__ void unpk8(int4 r, float* a) {
  a[0] = __uint_as_float(((u32)r.x) << 16);
  a[1] = __uint_as_float(((u32)r.x) & 0xffff0000u);
  a[2] = __uint_as_float(((u32)r.y) << 16);
  a[3] = __uint_as_float(((u32)r.y) & 0xffff0000u);
  a[4] = __uint_as_float(((u32)r.z) << 16);
  a[5] = __uint_as_float(((u32)r.z) & 0xffff0000u);
  a[6] = __uint_as_float(((u32)r.w) << 16);
  a[7] = __uint_as_float(((u32)r.w) & 0xffff0000u);
}

/* ---------------- kernel T: transpose weights [O][I] -> [Ipad][O], zero pad rows -------- */
__global__ __launch_bounds__(256) void kT(const float* __restrict__ w, float* __restrict__ wT,
                                          int O, int I, int Ipad) {
  int idx = blockIdx.x * 256 + threadIdx.x;
  int total = Ipad * O;
  if (idx >= total) return;
  int i = idx / O;
  int o = idx - i * O;
  wT[idx] = (i < I) ? w[o * I + i] : 0.f;
}

/* ---------------- kernel A: top-3 nearest SOM nodes per point + count/sum atomics ------- */
__global__ __launch_bounds__(256) void kA(const float* __restrict__ x, const float* __restrict__ node,
                                          int* __restrict__ idx_buf, int* __restrict__ cnt,
                                          float* __restrict__ sums) {
#pragma clang fp contract(off)
  __shared__ float ns[3][64];
  int b = blockIdx.y;
  int t = threadIdx.x;
  if (t < 192) { int c = t >> 6, m = t & 63; ns[c][m] = node[(b * 3 + c) * 64 + m]; }
  __syncthreads();
  int n = blockIdx.x * 256 + t;
  float x0 = x[(b * 3 + 0) * NQ + n];
  float x1 = x[(b * 3 + 1) * NQ + n];
  float x2 = x[(b * 3 + 2) * NQ + n];
  float d0 = 3.4e38f, d1 = 3.4e38f, d2 = 3.4e38f;
  int i0 = 0, i1 = 0, i2 = 0;
  for (int m = 0; m < 64; ++m) {
    float da = ns[0][m] - x0;
    float db = ns[1][m] - x1;
    float dc = ns[2][m] - x2;
    float d = da * da + db * db + dc * dc;
    if (d < d0)      { d2 = d1; i2 = i1; d1 = d0; i1 = i0; d0 = d; i0 = m; }
    else if (d < d1) { d2 = d1; i2 = i1; d1 = d;  i1 = m; }
    else if (d < d2) { d2 = d;  i2 = m; }
  }
  int base = (b * NQ + n) * 3;
  idx_buf[base + 0] = i0; idx_buf[base + 1] = i1; idx_buf[base + 2] = i2;
  int ms[3] = {i0, i1, i2};
  #pragma unroll
  for (int j = 0; j < 3; ++j) {
    int s = b * 64 + ms[j];
    atomicAdd(&cnt[s], 1);
    atomicAdd(&sums[s * 3 + 0], x0);
    atomicAdd(&sums[s * 3 + 1], x1);
    atomicAdd(&sums[s * 3 + 2], x2);
  }
}

/* ---------------- kernel B: prefix sums, chunk table, cluster means --------------------- */
__global__ __launch_bounds__(256) void kB(const int* __restrict__ cnt, const float* __restrict__ sums,
                                          int* __restrict__ offs, int* __restrict__ cursor,
                                          int* __restrict__ nchunks, int* __restrict__ chunk_tab,
                                          float* __restrict__ mean) {
  int t = threadIdx.x;
  if (t == 0) {
    int run = 0, nch = 0;
    for (int s = 0; s < SEGS; ++s) {
      offs[s] = run;
      int c = cnt[s];
      int st = run;
      run += c;
      while (c > 0) {
        int l = c > 64 ? 64 : c;
        chunk_tab[2 * nch]     = (s << 16) | l;
        chunk_tab[2 * nch + 1] = st;
        st += l; c -= l; ++nch;
      }
    }
    offs[SEGS] = run;
    nchunks[0] = nch;
  }
  __syncthreads();
  for (int i = t; i < SEGS; i += 256) cursor[i] = offs[i];
  for (int i = t; i < SEGS * 3; i += 256) {
    int s = i / 3;
    mean[i] = sums[i] / ((float)cnt[s] + 1e-5f);
  }
}

/* ---------------- kernel A2: bucket points by (b,node) ---------------------------------- */
__global__ __launch_bounds__(256) void kA2(const int* __restrict__ idx_buf, int* __restrict__ cursor,
                                           int* __restrict__ perm) {
  int b = blockIdx.y;
  int n = blockIdx.x * 256 + threadIdx.x;
  int base = (b * NQ + n) * 3;
  #pragma unroll
  for (int j = 0; j < 3; ++j) {
    int m = idx_buf[base + j];
    int pos = atomicAdd(&cursor[b * 64 + m], 1);
    perm[pos] = (b << 21) | (n << 8) | (j << 6) | m;
  }
}

/* ---------------- kernel C: fused PointResNet + per-node scatter-max -------------------- */
template<int I, int O, int SSTR, int DSTR, int SOFF, int DOFF>
__device__ __forceinline__ void layer_mid(const float* __restrict__ W, const float* __restrict__ Bv,
                                          const u16* s_src, u16* s_dst, int lane, int wid) {
  constexpr int OW = O / 8;
  const u16* srow = s_src + lane * SSTR + SOFF;
  u16* drow = s_dst + lane * DSTR + DOFF;
  #pragma unroll
  for (int g = 0; g < OW / 8; ++g) {
    const int o0 = wid * OW + g * 8;
    float acc[8];
    #pragma unroll
    for (int oi = 0; oi < 8; ++oi) acc[oi] = Bv[o0 + oi];
    #pragma unroll 2
    for (int i0 = 0; i0 < I; i0 += 8) {
      int4 r = *(const int4*)(srow + i0);
      float a[8];
      unpk8(r, a);
      #pragma unroll
      for (int oi = 0; oi < 8; ++oi) {
        const float* wr = W + (o0 + oi) * I + i0;
        #pragma unroll
        for (int k = 0; k < 8; ++k) acc[oi] = fmaf(wr[k], a[k], acc[oi]);
      }
    }
    u32 p0 = pk2(fmaxf(acc[0], 0.f), fmaxf(acc[1], 0.f));
    u32 p1 = pk2(fmaxf(acc[2], 0.f), fmaxf(acc[3], 0.f));
    u32 p2 = pk2(fmaxf(acc[4], 0.f), fmaxf(acc[5], 0.f));
    u32 p3 = pk2(fmaxf(acc[6], 0.f), fmaxf(acc[7], 0.f));
    *(int4*)(drow + o0) = make_int4((int)p0, (int)p1, (int)p2, (int)p3);
  }
}

__global__ __launch_bounds__(512) void kC(
    const float* __restrict__ x, const float* __restrict__ sn,
    const float* __restrict__ mean, const int* __restrict__ perm,
    const int* __restrict__ chunk_tab, const int* __restrict__ nchunks,
    const float* __restrict__ w0, const float* __restrict__ b0v,
    const float* __restrict__ w1, const float* __restrict__ b1v,
    const float* __restrict__ w2, const float* __restrict__ b2v,
    const float* __restrict__ w3, const float* __restrict__ b3v,
    float* __restrict__ node_max, float* __restrict__ fallback) {
  __shared__ u16 big_s[64 * C_BIG_STR];   /* cols 0..63 = h0, 64..319 = h2 */
  __shared__ u16 h1_s[64 * C_H1_STR];
  __shared__ float in_s[64][8];
  __shared__ int flag_s[64];
  int blk = blockIdx.x;
  if (blk >= nchunks[0]) return;
  int e0    = chunk_tab[2 * blk];
  int start = chunk_tab[2 * blk + 1];
  int seg = e0 >> 16, len = e0 & 0xffff;
  int b = seg >> 6;
  int tid = threadIdx.x;
  if (tid < 64) {
    float v0 = 0, v1 = 0, v2 = 0, v3 = 0, v4 = 0, v5 = 0;
    int fl = 0;
    if (tid < len) {
      int rec = perm[start + tid];
      int n = (rec >> 8) & 0x1fff;
      int j = (rec >> 6) & 3;
      const float* xb = x  + (size_t)b * 3 * NQ;
      const float* sb = sn + (size_t)b * 3 * NQ;
      v0 = xb[n]            - mean[seg * 3 + 0];
      v1 = xb[NQ + n]       - mean[seg * 3 + 1];
      v2 = xb[2 * NQ + n]   - mean[seg * 3 + 2];
      v3 = sb[n]; v4 = sb[NQ + n]; v5 = sb[2 * NQ + n];
      fl = (n == 0 && j == 0) ? 1 : 0;
    }
    in_s[tid][0] = v0; in_s[tid][1] = v1; in_s[tid][2] = v2;
    in_s[tid][3] = v3; in_s[tid][4] = v4; in_s[tid][5] = v5;
    in_s[tid][6] = 0.f; in_s[tid][7] = 0.f;
    flag_s[tid] = fl;
  }
  __syncthreads();
  int wid  = __builtin_amdgcn_readfirstlane((int)(threadIdx.x >> 6));
  int lane = (int)(threadIdx.x & 63);

  /* layer1: 6 -> 64 (wave w owns o = w*8 .. w*8+7) */
  {
    float a0 = in_s[lane][0], a1 = in_s[lane][1], a2 = in_s[lane][2];
    float a3 = in_s[lane][3], a4 = in_s[lane][4], a5 = in_s[lane][5];
    int o0 = wid * 8;
    u32 pk[4];
    #pragma unroll
    for (int q = 0; q < 4; ++q) {
      float sA = b0v[o0 + 2 * q + 0];
      float sB = b0v[o0 + 2 * q + 1];
      const float* wA = w0 + (o0 + 2 * q) * 6;
      const float* wB = wA + 6;
      sA = fmaf(wA[0], a0, sA); sA = fmaf(wA[1], a1, sA); sA = fmaf(wA[2], a2, sA);
      sA = fmaf(wA[3], a3, sA); sA = fmaf(wA[4], a4, sA); sA = fmaf(wA[5], a5, sA);
      sB = fmaf(wB[0], a0, sB); sB = fmaf(wB[1], a1, sB); sB = fmaf(wB[2], a2, sB);
      sB = fmaf(wB[3], a3, sB); sB = fmaf(wB[4], a4, sB); sB = fmaf(wB[5], a5, sB);
      pk[q] = pk2(fmaxf(sA, 0.f), fmaxf(sB, 0.f));
    }
    *(int4*)&big_s[lane * C_BIG_STR + o0] = make_int4((int)pk[0], (int)pk[1], (int)pk[2], (int)pk[3]);
  }
  __syncthreads();
  layer_mid<64, 128, C_BIG_STR, C_H1_STR, 0, 0>(w1, b1v, big_s, h1_s, lane, wid);
  __syncthreads();
  layer_mid<128, 256, C_H1_STR, C_BIG_STR, 0, 64>(w2, b2v, h1_s, big_s, lane, wid);
  __syncthreads();
  /* layer4: 320 -> 384, epilogue: wave max-reduce + one atomic per channel */
  {
    const u16* srow = big_s + lane * C_BIG_STR;
    int valid = (lane < len) ? 1 : 0;
    int fl = flag_s[lane];
    #pragma unroll
    for (int g = 0; g < 6; ++g) {
      int o0 = wid * 48 + g * 8;
      float acc[8];
      #pragma unroll
      for (int oi = 0; oi < 8; ++oi) acc[oi] = b3v[o0 + oi];
      #pragma unroll 2
      for (int i0 = 0; i0 < 320; i0 += 8) {
        int4 r = *(const int4*)(srow + i0);
        float a[8];
        unpk8(r, a);
        #pragma unroll
        for (int oi = 0; oi < 8; ++oi) {
          const float* wr = w3 + (o0 + oi) * 320 + i0;
          #pragma unroll
          for (int k = 0; k < 8; ++k) acc[oi] = fmaf(wr[k], a[k], acc[oi]);
        }
      }
      #pragma unroll
      for (int oi = 0; oi < 8; ++oi) {
        float v = fmaxf(acc[oi], 0.f);
        if (fl) fallback[b * 384 + o0 + oi] = v;   /* first[:,:,0] */
        if (!valid) v = 0.f;                       /* pad lanes: relu>=0 so 0 is identity */
        #pragma unroll
        for (int d = 32; d >= 1; d >>= 1) v = fmaxf(v, __shfl_xor(v, d));
        if (lane == 0)
          atomicMax((int*)&node_max[(size_t)seg * 384 + o0 + oi], __float_as_int(v));
      }
    }
  }
}

/* ---------------- kernel D: SOM-neighborhood KNN module -------------------------------- */
__global__ __launch_bounds__(256) void kD(
    const float* __restrict__ mean, const float* __restrict__ node_max,
    const float* __restrict__ fallback, const int* __restrict__ cnt,
    const int* __restrict__ knn_I,
    const float* __restrict__ w0T, const float* __restrict__ b0v,
    const float* __restrict__ w1T, const float* __restrict__ b1v,
    float* __restrict__ knn_feat, float* __restrict__ center_out) {
  __shared__ float aug_s[9][388];
  __shared__ float g1_s[9][512];
  __shared__ int nb_s[9];
  __shared__ float ctr_s[3];
  int seg = blockIdx.x;
  int b = seg >> 6;
  int t = threadIdx.x;
  if (t < 9) nb_s[t] = knn_I[seg * 9 + t];
  __syncthreads();
  if (t < 27) { int kk = t / 3, c = t - kk * 3; aug_s[kk][c] = mean[(b * 64 + nb_s[kk]) * 3 + c]; }
  __syncthreads();
  if (t < 3) {
    float s = 0.f;
    #pragma unroll
    for (int kk = 0; kk < 9; ++kk) s += aug_s[kk][t];
    s *= (1.f / 9.f);
    ctr_s[t] = s;
    center_out[seg * 3 + t] = s;
  }
  __syncthreads();
  if (t < 27) { int kk = t / 3, c = t - kk * 3; aug_s[kk][c] -= ctr_s[c]; }
  for (int kk = 0; kk < 9; ++kk) {
    int nb = nb_s[kk];
    const float* src = (cnt[b * 64 + nb] > 0) ? (node_max + (size_t)(b * 64 + nb) * 384)
                                              : (fallback + (size_t)b * 384);
    for (int i = t; i < 384; i += 256) aug_s[kk][3 + i] = src[i];
  }
  if (t < 9) aug_s[t][387] = 0.f;
  __syncthreads();
  /* layer1: 387 -> 512 (o = t, t+256) */
  {
    float acc0[9], acc1[9];
    float bb0 = b0v[t], bb1 = b0v[t + 256];
    #pragma unroll
    for (int kk = 0; kk < 9; ++kk) { acc0[kk] = bb0; acc1[kk] = bb1; }
    for (int i = 0; i < 388; i += 2) {
      float wA0 = w0T[i * 512 + t],        wB0 = w0T[i * 512 + t + 256];
      float wA1 = w0T[(i + 1) * 512 + t],  wB1 = w0T[(i + 1) * 512 + t + 256];
      #pragma unroll
      for (int kk = 0; kk < 9; ++kk) {
        float2 a = *(const float2*)&aug_s[kk][i];
        acc0[kk] = fmaf(wA0, a.x, acc0[kk]); acc1[kk] = fmaf(wB0, a.x, acc1[kk]);
        acc0[kk] = fmaf(wA1, a.y, acc0[kk]); acc1[kk] = fmaf(wB1, a.y, acc1[kk]);
      }
    }
    #pragma unroll
    for (int kk = 0; kk < 9; ++kk) {
      g1_s[kk][t]       = fmaxf(acc0[kk], 0.f);
      g1_s[kk][t + 256] = fmaxf(acc1[kk], 0.f);
    }
  }
  __syncthreads();
  /* layer2: 512 -> 512, max over kk */
  {
    float acc0[9], acc1[9];
    float bb0 = b1v[t], bb1 = b1v[t + 256];
    #pragma unroll
    for (int kk = 0; kk < 9; ++kk) { acc0[kk] = bb0; acc1[kk] = bb1; }
    for (int i = 0; i < 512; i += 2) {
      float wA0 = w1T[i * 512 + t],        wB0 = w1T[i * 512 + t + 256];
      float wA1 = w1T[(i + 1) * 512 + t],  wB1 = w1T[(i + 1) * 512 + t + 256];
      #pragma unroll
      for (int kk = 0; kk < 9; ++kk) {
        float2 a = *(const float2*)&g1_s[kk][i];
        acc0[kk] = fmaf(wA0, a.x, acc0[kk]); acc1[kk] = fmaf(wB0, a.x, acc1[kk]);
        acc0[kk] = fmaf(wA1, a.y, acc0[kk]); acc1[kk] = fmaf(wB1, a.y, acc1[kk]);
      }
    }
    float m0 = acc0[0], m1 = acc1[0];
    #pragma unroll
    for (int kk = 1; kk < 9; ++kk) { m0 = fmaxf(m0, acc0[kk]); m1 = fmaxf(m1, acc1[kk]); }
    knn_feat[(size_t)seg * 512 + t]       = fmaxf(m0, 0.f);
    knn_feat[(size_t)seg * 512 + t + 256] = fmaxf(m1, 0.f);
  }
}

/* ---------------- kernel E: final PointNet + global max pool --------------------------- */
__global__ __launch_bounds__(256) void kE(
    const float* __restrict__ center, const float* __restrict__ knn_feat,
    const float* __restrict__ w0T, const float* __restrict__ b0v,
    const float* __restrict__ w1T, const float* __restrict__ b1v,
    float* __restrict__ out) {
  __shared__ float in_s[8][516];
  __shared__ float mid_s[8][772];
  int blk = blockIdx.x;    /* 64 blocks x 8 cols */
  int t = threadIdx.x;
  int col0 = blk * 8;
  int b = col0 >> 6;
  for (int c8 = 0; c8 < 8; ++c8) {
    int seg = col0 + c8;
    if (t < 3) in_s[c8][t] = center[seg * 3 + t];
    for (int i = t; i < 512; i += 256) in_s[c8][3 + i] = knn_feat[(size_t)seg * 512 + i];
    if (t == 0) in_s[c8][515] = 0.f;
  }
  __syncthreads();
  /* layer1: 515 -> 768 (o = t + 256q, q<3) */
  {
    float acc[3][8];
    #pragma unroll
    for (int q = 0; q < 3; ++q) {
      float bb = b0v[t + 256 * q];
      #pragma unroll
      for (int c8 = 0; c8 < 8; ++c8) acc[q][c8] = bb;
    }
    for (int i = 0; i < 516; i += 2) {
      float w00 = w0T[i * 768 + t], w01 = w0T[i * 768 + t + 256], w02 = w0T[i * 768 + t + 512];
      float w10 = w0T[(i + 1) * 768 + t], w11 = w0T[(i + 1) * 768 + t + 256], w12 = w0T[(i + 1) * 768 + t + 512];
      #pragma unroll
      for (int c8 = 0; c8 < 8; ++c8) {
        float2 a = *(const float2*)&in_s[c8][i];
        acc[0][c8] = fmaf(w00, a.x, acc[0][c8]); acc[0][c8] = fmaf(w10, a.y, acc[0][c8]);
        acc[1][c8] = fmaf(w01, a.x, acc[1][c8]); acc[1][c8] = fmaf(w11, a.y, acc[1][c8]);
        acc[2][c8] = fmaf(w02, a.x, acc[2][c8]); acc[2][c8] = fmaf(w12, a.y, acc[2][c8]);
      }
    }
    #pragma unroll
    for (int q = 0; q < 3; ++q)
      #pragma unroll
      for (int c8 = 0; c8 < 8; ++c8)
        mid_s[c8][t + 256 * q] = fmaxf(acc[q][c8], 0.f);
  }
  __syncthreads();
  /* layer2: 768 -> 1024 (o = t + 256q, q<4), max over 8 cols -> atomic max */
  {
    float acc[4][8];
    #pragma unroll
    for (int q = 0; q < 4; ++q) {
      float bb = b1v[t + 256 * q];
      #pragma unroll
      for (int c8 = 0; c8 < 8; ++c8) acc[q][c8] = bb;
    }
    for (int i = 0; i < 768; i += 2) {
      float wq0[4], wq1[4];
      #pragma unroll
      for (int q = 0; q < 4; ++q) {
        wq0[q] = w1T[i * 1024 + t + 256 * q];
        wq1[q] = w1T[(i + 1) * 1024 + t + 256 * q];
      }
      #pragma unroll
      for (int c8 = 0; c8 < 8; ++c8) {
        float2 a = *(const float2*)&mid_s[c8][i];
        #pragma unroll
        for (int q = 0; q < 4; ++q) {
          acc[q][c8] = fmaf(wq0[q], a.x, acc[q][c8]);
          acc[q][c8] = fmaf(wq1[q], a.y, acc[q][c8]);
        }
      }
    }
    #pragma unroll
    for (int q = 0; q < 4; ++q) {
      float v = acc[q][0];
      #pragma unroll
      for (int c8 = 1; c8 < 8; ++c8) v = fmaxf(v, acc[q][c8]);
      v = fmaxf(v, 0.f);
      atomicMax((int*)&out[b * 1024 + t + 256 * q], __float_as_int(v));
    }
  }
}

/* ---------------- launcher -------------------------------------------------------------- */
extern "C" void kernel_launch(void* const* d_in, const int* in_sizes, int n_in,
                              void* d_out, int out_size, void* d_ws, size_t ws_size,
                              hipStream_t stream) {
  const float* x      = (const float*)d_in[0];
  const float* sn     = (const float*)d_in[1];
  const float* node   = (const float*)d_in[2];
  const int*   knn_I  = (const int*)d_in[3];
  const float* pr_w0  = (const float*)d_in[4];
  const float* pr_b0  = (const float*)d_in[5];
  const float* pr_w1  = (const float*)d_in[6];
  const float* pr_b1  = (const float*)d_in[7];
  const float* pr_w2  = (const float*)d_in[8];
  const float* pr_b2  = (const float*)d_in[9];
  const float* pr_w3  = (const float*)d_in[10];
  const float* pr_b3  = (const float*)d_in[11];
  const float* knn_w0 = (const float*)d_in[12];
  const float* knn_b0 = (const float*)d_in[13];
  const float* knn_w1 = (const float*)d_in[14];
  const float* knn_b1 = (const float*)d_in[15];
  const float* fin_w0 = (const float*)d_in[16];
  const float* fin_b0 = (const float*)d_in[17];
  const float* fin_w1 = (const float*)d_in[18];
  const float* fin_b1 = (const float*)d_in[19];
  float* out = (float*)d_out;
  char* ws = (char*)d_ws;

  int*   idx_buf   = (int*)(ws + OFF_IDX);
  int*   perm      = (int*)(ws + OFF_PERM);
  int*   cnt       = (int*)(ws + OFF_CNT);
  float* sums      = (float*)(ws + OFF_SUMS);
  int*   offs      = (int*)(ws + OFF_OFFS);
  int*   cursor    = (int*)(ws + OFF_CURSOR);
  int*   nchunks   = (int*)(ws + OFF_NCHUNK);
  int*   chunk_tab = (int*)(ws + OFF_CHUNKTAB);
  float* mean      = (float*)(ws + OFF_MEAN);
  float* fallback  = (float*)(ws + OFF_FALLBACK);
  float* node_max  = (float*)(ws + OFF_NODEMAX);
  float* centerb   = (float*)(ws + OFF_CENTER);
  float* knn_feat  = (float*)(ws + OFF_KNNFEAT);
  float* w0T_knn   = (float*)(ws + OFF_W0T_KNN);
  float* w1T_knn   = (float*)(ws + OFF_W1T_KNN);
  float* w0T_fin   = (float*)(ws + OFF_W0T_FIN);
  float* w1T_fin   = (float*)(ws + OFF_W1T_FIN);

  hipMemsetAsync(ws + OFF_CNT, 0, 8192, stream);                 /* cnt + sums */
  hipMemsetAsync(ws + OFF_NODEMAX, 0, (size_t)SEGS * 384 * 4, stream);
  hipMemsetAsync(d_out, 0, (size_t)out_size * 4, stream);

  kT<<<(388 * 512 + 255) / 256, 256, 0, stream>>>(knn_w0, w0T_knn, 512, 387, 388);
  kT<<<(512 * 512 + 255) / 256, 256, 0, stream>>>(knn_w1, w1T_knn, 512, 512, 512);
  kT<<<(516 * 768 + 255) / 256, 256, 0, stream>>>(fin_w0, w0T_fin, 768, 515, 516);
  kT<<<(768 * 1024 + 255) / 256, 256, 0, stream>>>(fin_w1, w1T_fin, 1024, 768, 768);

  dim3 gA(NQ / 256, BQ);
  kA<<<gA, 256, 0, stream>>>(x, node, idx_buf, cnt, sums);
  kB<<<1, 256, 0, stream>>>(cnt, sums, offs, cursor, nchunks, chunk_tab, mean);
  kA2<<<gA, 256, 0, stream>>>(idx_buf, cursor, perm);
  kC<<<MAXCHUNK, 512, 0, stream>>>(x, sn, mean, perm, chunk_tab, nchunks,
                                   pr_w0, pr_b0, pr_w1, pr_b1, pr_w2, pr_b2, pr_w3, pr_b3,
                                   node_max, fallback);
  kD<<<SEGS, 256, 0, stream>>>(mean, node_max, fallback, cnt, knn_I,
                               w0T_knn, knn_b0, w1T_knn, knn_b1, knn_feat, centerb);
  kE<<<64, 256, 0, stream>>>(centerb, knn_feat, w0T_fin, fin_b0, w1T_fin, fin_b1, out);
}

// Round 3
// 717.734 us; speedup vs baseline: 3.1980x; 3.1980x over previous
//
#include <hip/hip_runtime.h>

typedef unsigned short u16;
typedef unsigned int   u32;
typedef _Float16 f16;
typedef _Float16 f16x8 __attribute__((ext_vector_type(8)));
typedef _Float16 f16x4 __attribute__((ext_vector_type(4)));
typedef float    f32x4 __attribute__((ext_vector_type(4)));

#define BQ 8
#define NQ 8192
#define MQ 64
#define SEGS (BQ*MQ)        /* 512 */
#define MAXCHUNK 3584
#define KBA 10              /* k-blocks in concat(h0,h2) = 320/32 */

/* ---- workspace layout (bytes) ---- */
#define OFF_IDX      (size_t)0         /* int[B*N*3]      786432 */
#define OFF_PERM     (size_t)786432    /* int[196608]     786432 */
#define OFF_CNT      (size_t)1572864   /* int[512]          2048 */
#define OFF_SUMS     (size_t)1574912   /* float[1536]       6144 */
#define OFF_OFFS     (size_t)1581056   /* int[513]     pad  2304 */
#define OFF_CURSOR   (size_t)1583360   /* int[512]          2048 */
#define OFF_NCHUNK   (size_t)1585408   /* int[64]            256 */
#define OFF_CHUNKTAB (size_t)1585664   /* int[2*3584]      28672 */
#define OFF_MEAN     (size_t)1614336   /* float[1536]       6144 */
#define OFF_FALLBACK (size_t)1620480   /* float[8*384]     12288 */
#define OFF_NODEMAX  (size_t)1632768   /* float[512*384]  786432 */
#define OFF_CENTER   (size_t)2419200   /* float[512*3]      6144 */
#define OFF_KNNFEAT  (size_t)2425344   /* float[512*512] 1048576 */
#define OFF_W0T_KNN  (size_t)3473920   /* float[388*512]  794624 */
#define OFF_W1T_KNN  (size_t)4268544   /* float[512*512] 1048576 */
#define OFF_W0T_FIN  (size_t)5317120   /* float[516*768] 1585152 */
#define OFF_W1T_FIN  (size_t)6902272   /* float[768*1024]3145728 */
#define OFF_W1P      (size_t)10048000  /* f16 frag 128x64   16384 */
#define OFF_W2P      (size_t)10064384  /* f16 frag 256x128  65536 */
#define OFF_W3P      (size_t)10129920  /* f16 frag 384x320 245760 */

/* ---------------- fused weight prep: 4 transposes + 3 MFMA-frag packs ------------------ */
__device__ __forceinline__ void wtrans(const float* __restrict__ w, float* __restrict__ wT,
                                       int O, int I, int Ipad, int idx) {
  int total = Ipad * O;
  if (idx >= total) return;
  int i = idx / O;
  int o = idx - i * O;
  wT[idx] = (i < I) ? w[o * I + i] : 0.f;
}
/* A-frag pack: out[((ct*KB+kb)*64+l)*8+e] = W[ct*16+(l&15)][kb*32+(l>>4)*8+e] */
__device__ __forceinline__ void wpack(const float* __restrict__ W, f16* __restrict__ out,
                                      int K, int KB, int idx, int total) {
  if (idx >= total) return;
  int e  = idx & 7;
  int l  = (idx >> 3) & 63;
  int kb = (idx >> 9) % KB;
  int ct = idx / (KB << 9);
  int row = ct * 16 + (l & 15);
  int col = kb * 32 + ((l >> 4) << 3) + e;
  out[idx] = (f16)W[row * K + col];
}
__global__ __launch_bounds__(256) void kW(
    const float* knn_w0, const float* knn_w1, const float* fin_w0, const float* fin_w1,
    const float* pr_w1, const float* pr_w2, const float* pr_w3,
    float* w0T_knn, float* w1T_knn, float* w0T_fin, float* w1T_fin,
    f16* w1p, f16* w2p, f16* w3p) {
  int blk = blockIdx.x;
  int t = threadIdx.x;
  if (blk < 776)       wtrans(knn_w0, w0T_knn, 512, 387, 388, blk * 256 + t);
  else if (blk < 1800) wtrans(knn_w1, w1T_knn, 512, 512, 512, (blk - 776) * 256 + t);
  else if (blk < 3348) wtrans(fin_w0, w0T_fin, 768, 515, 516, (blk - 1800) * 256 + t);
  else if (blk < 6420) wtrans(fin_w1, w1T_fin, 1024, 768, 768, (blk - 3348) * 256 + t);
  else if (blk < 6452) wpack(pr_w1, w1p, 64, 2, (blk - 6420) * 256 + t, 8192);
  else if (blk < 6580) wpack(pr_w2, w2p, 128, 4, (blk - 6452) * 256 + t, 32768);
  else                 wpack(pr_w3, w3p, 320, 10, (blk - 6580) * 256 + t, 122880);
}

/* ---------------- kernel A: top-3 nearest SOM nodes per point + count/sum atomics ------- */
__global__ __launch_bounds__(256) void kA(const float* __restrict__ x, const float* __restrict__ node,
                                          int* __restrict__ idx_buf, int* __restrict__ cnt,
                                          float* __restrict__ sums) {
#pragma clang fp contract(off)
  __shared__ float ns[3][64];
  int b = blockIdx.y;
  int t = threadIdx.x;
  if (t < 192) { int c = t >> 6, m = t & 63; ns[c][m] = node[(b * 3 + c) * 64 + m]; }
  __syncthreads();
  int n = blockIdx.x * 256 + t;
  float x0 = x[(b * 3 + 0) * NQ + n];
  float x1 = x[(b * 3 + 1) * NQ + n];
  float x2 = x[(b * 3 + 2) * NQ + n];
  float d0 = 3.4e38f, d1 = 3.4e38f, d2 = 3.4e38f;
  int i0 = 0, i1 = 0, i2 = 0;
  for (int m = 0; m < 64; ++m) {
    float da = ns[0][m] - x0;
    float db = ns[1][m] - x1;
    float dc = ns[2][m] - x2;
    float d = da * da + db * db + dc * dc;
    if (d < d0)      { d2 = d1; i2 = i1; d1 = d0; i1 = i0; d0 = d; i0 = m; }
    else if (d < d1) { d2 = d1; i2 = i1; d1 = d;  i1 = m; }
    else if (d < d2) { d2 = d;  i2 = m; }
  }
  int base = (b * NQ + n) * 3;
  idx_buf[base + 0] = i0; idx_buf[base + 1] = i1; idx_buf[base + 2] = i2;
  int ms[3] = {i0, i1, i2};
  #pragma unroll
  for (int j = 0; j < 3; ++j) {
    int s = b * 64 + ms[j];
    atomicAdd(&cnt[s], 1);
    atomicAdd(&sums[s * 3 + 0], x0);
    atomicAdd(&sums[s * 3 + 1], x1);
    atomicAdd(&sums[s * 3 + 2], x2);
  }
}

/* ---------------- kernel B: prefix sums, chunk table, cluster means --------------------- */
__global__ __launch_bounds__(256) void kB(const int* __restrict__ cnt, const float* __restrict__ sums,
                                          int* __restrict__ offs, int* __restrict__ cursor,
                                          int* __restrict__ nchunks, int* __restrict__ chunk_tab,
                                          float* __restrict__ mean) {
  int t = threadIdx.x;
  if (t == 0) {
    int run = 0, nch = 0;
    for (int s = 0; s < SEGS; ++s) {
      offs[s] = run;
      int c = cnt[s];
      int st = run;
      run += c;
      while (c > 0) {
        int l = c > 64 ? 64 : c;
        chunk_tab[2 * nch]     = (s << 16) | l;
        chunk_tab[2 * nch + 1] = st;
        st += l; c -= l; ++nch;
      }
    }
    offs[SEGS] = run;
    nchunks[0] = nch;
  }
  __syncthreads();
  for (int i = t; i < SEGS; i += 256) cursor[i] = offs[i];
  for (int i = t; i < SEGS * 3; i += 256) {
    int s = i / 3;
    mean[i] = sums[i] / ((float)cnt[s] + 1e-5f);
  }
}

/* ---------------- kernel A2: bucket points by (b,node) ---------------------------------- */
__global__ __launch_bounds__(256) void kA2(const int* __restrict__ idx_buf, int* __restrict__ cursor,
                                           int* __restrict__ perm) {
  int b = blockIdx.y;
  int n = blockIdx.x * 256 + threadIdx.x;
  int base = (b * NQ + n) * 3;
  #pragma unroll
  for (int j = 0; j < 3; ++j) {
    int m = idx_buf[base + j];
    int pos = atomicAdd(&cursor[b * 64 + m], 1);
    perm[pos] = (b << 21) | (n << 8) | (j << 6) | m;
  }
}

/* ---------------- kernel C: fused MFMA PointResNet + per-node scatter-max --------------- */
__global__ __launch_bounds__(512) void kC(
    const float* __restrict__ x, const float* __restrict__ sn,
    const float* __restrict__ mean, const int* __restrict__ perm,
    const int* __restrict__ chunk_tab, const int* __restrict__ nchunks,
    const float* __restrict__ w0, const float* __restrict__ b0v,
    const f16* __restrict__ w1p, const float* __restrict__ b1v,
    const f16* __restrict__ w2p, const float* __restrict__ b2v,
    const f16* __restrict__ w3p, const float* __restrict__ b3v,
    float* __restrict__ node_max, float* __restrict__ fallback) {
  /* bufA: B-frags of concat(h0,h2): [pt 4][kb 10][lane 64][e 8]  (40960 B)
     bufH1: B-frags of h1:           [pt 4][kb 4][lane 64][e 8]   (16384 B) */
  __shared__ __align__(16) f16 bufA[4 * KBA * 64 * 8];
  __shared__ __align__(16) f16 bufH1[4 * 4 * 64 * 8];
  __shared__ float in_s[6][64];
  __shared__ int flag_s[64];
  int blk = blockIdx.x;
  if (blk >= nchunks[0]) return;
  int e0    = chunk_tab[2 * blk];
  int start = chunk_tab[2 * blk + 1];
  int seg = e0 >> 16, len = e0 & 0xffff;
  int b = seg >> 6;
  int tid = threadIdx.x;
  if (tid < 64) {
    float v0 = 0, v1 = 0, v2 = 0, v3 = 0, v4 = 0, v5 = 0;
    int fl = 0;
    if (tid < len) {
      int rec = perm[start + tid];
      int n = (rec >> 8) & 0x1fff;
      int j = (rec >> 6) & 3;
      const float* xb = x  + (size_t)b * 3 * NQ;
      const float* sb = sn + (size_t)b * 3 * NQ;
      v0 = xb[n]          - mean[seg * 3 + 0];
      v1 = xb[NQ + n]     - mean[seg * 3 + 1];
      v2 = xb[2 * NQ + n] - mean[seg * 3 + 2];
      v3 = sb[n]; v4 = sb[NQ + n]; v5 = sb[2 * NQ + n];
      fl = (n == 0 && j == 0) ? 1 : 0;
    }
    in_s[0][tid] = v0; in_s[1][tid] = v1; in_s[2][tid] = v2;
    in_s[3][tid] = v3; in_s[4][tid] = v4; in_s[5][tid] = v5;
    flag_s[tid] = fl;
  }
  __syncthreads();
  int wid  = __builtin_amdgcn_readfirstlane(tid >> 6);
  int lane = tid & 63;
  int pcol = lane & 15;
  int g    = lane >> 4;

  /* ---- L1 (scalar): 6 -> 64, point = lane, channels wid*8..+7; write h0 frags (kb 0..1) */
  {
    float a0 = in_s[0][lane], a1 = in_s[1][lane], a2 = in_s[2][lane];
    float a3 = in_s[3][lane], a4 = in_s[4][lane], a5 = in_s[5][lane];
    f16x8 v;
    #pragma unroll
    for (int i = 0; i < 8; ++i) {
      const float* wr = w0 + (wid * 8 + i) * 6;
      float s = b0v[wid * 8 + i];
      s = fmaf(wr[0], a0, s); s = fmaf(wr[1], a1, s); s = fmaf(wr[2], a2, s);
      s = fmaf(wr[3], a3, s); s = fmaf(wr[4], a4, s); s = fmaf(wr[5], a5, s);
      v[i] = (f16)fmaxf(s, 0.f);
    }
    int kb = wid >> 2, q = wid & 3;
    *(f16x8*)&bufA[(((lane >> 4) * KBA + kb) * 64 + pcol + 16 * q) * 8] = v;
  }
  __syncthreads();

  /* ---- L2 (MFMA): 64 -> 128, wave owns ctile = wid ---- */
  f32x4 acc1[4] = {};
  #pragma unroll
  for (int kb = 0; kb < 2; ++kb) {
    f16x8 af = *(const f16x8*)(w1p + (size_t)((wid * 2 + kb) * 64 + lane) * 8);
    #pragma unroll
    for (int pt = 0; pt < 4; ++pt) {
      f16x8 bf = *(const f16x8*)&bufA[((pt * KBA + kb) * 64 + lane) * 8];
      acc1[pt] = __builtin_amdgcn_mfma_f32_16x16x32_f16(af, bf, acc1[pt], 0, 0, 0);
    }
  }
  {
    float4 bb = *(const float4*)&b1v[wid * 16 + g * 4];
    int kbo = wid >> 1;
    int q   = ((wid & 1) << 1) + (g >> 1);
    int ee  = (g & 1) * 4;
    #pragma unroll
    for (int pt = 0; pt < 4; ++pt) {
      f16x4 v;
      v[0] = (f16)fmaxf(acc1[pt][0] + bb.x, 0.f);
      v[1] = (f16)fmaxf(acc1[pt][1] + bb.y, 0.f);
      v[2] = (f16)fmaxf(acc1[pt][2] + bb.z, 0.f);
      v[3] = (f16)fmaxf(acc1[pt][3] + bb.w, 0.f);
      *(f16x4*)&bufH1[((pt * 4 + kbo) * 64 + pcol + 16 * q) * 8 + ee] = v;
    }
  }
  __syncthreads();

  /* ---- L3 (MFMA): 128 -> 256, wave owns ctiles 2*wid, 2*wid+1; output -> bufA kb 2+wid */
  f32x4 acc2[2][4] = {};
  #pragma unroll
  for (int kb = 0; kb < 4; ++kb) {
    f16x8 af0 = *(const f16x8*)(w2p + (size_t)(((wid * 2 + 0) * 4 + kb) * 64 + lane) * 8);
    f16x8 af1 = *(const f16x8*)(w2p + (size_t)(((wid * 2 + 1) * 4 + kb) * 64 + lane) * 8);
    #pragma unroll
    for (int pt = 0; pt < 4; ++pt) {
      f16x8 bf = *(const f16x8*)&bufH1[((pt * 4 + kb) * 64 + lane) * 8];
      acc2[0][pt] = __builtin_amdgcn_mfma_f32_16x16x32_f16(af0, bf, acc2[0][pt], 0, 0, 0);
      acc2[1][pt] = __builtin_amdgcn_mfma_f32_16x16x32_f16(af1, bf, acc2[1][pt], 0, 0, 0);
    }
  }
  {
    int kbo = 2 + wid;
    #pragma unroll
    for (int s = 0; s < 2; ++s) {
      float4 bb = *(const float4*)&b2v[(wid * 2 + s) * 16 + g * 4];
      int q  = 2 * s + (g >> 1);
      int ee = (g & 1) * 4;
      #pragma unroll
      for (int pt = 0; pt < 4; ++pt) {
        f16x4 v;
        v[0] = (f16)fmaxf(acc2[s][pt][0] + bb.x, 0.f);
        v[1] = (f16)fmaxf(acc2[s][pt][1] + bb.y, 0.f);
        v[2] = (f16)fmaxf(acc2[s][pt][2] + bb.z, 0.f);
        v[3] = (f16)fmaxf(acc2[s][pt][3] + bb.w, 0.f);
        *(f16x4*)&bufA[((pt * KBA + kbo) * 64 + pcol + 16 * q) * 8 + ee] = v;
      }
    }
  }
  __syncthreads();

  /* ---- L4 (MFMA): 320 -> 384, wave owns ctiles 3*wid..3*wid+2 ---- */
  f32x4 acc3[3][4] = {};
  #pragma unroll
  for (int kb = 0; kb < KBA; ++kb) {
    f16x8 af0 = *(const f16x8*)(w3p + (size_t)(((wid * 3 + 0) * KBA + kb) * 64 + lane) * 8);
    f16x8 af1 = *(const f16x8*)(w3p + (size_t)(((wid * 3 + 1) * KBA + kb) * 64 + lane) * 8);
    f16x8 af2 = *(const f16x8*)(w3p + (size_t)(((wid * 3 + 2) * KBA + kb) * 64 + lane) * 8);
    #pragma unroll
    for (int pt = 0; pt < 4; ++pt) {
      f16x8 bf = *(const f16x8*)&bufA[((pt * KBA + kb) * 64 + lane) * 8];
      acc3[0][pt] = __builtin_amdgcn_mfma_f32_16x16x32_f16(af0, bf, acc3[0][pt], 0, 0, 0);
      acc3[1][pt] = __builtin_amdgcn_mfma_f32_16x16x32_f16(af1, bf, acc3[1][pt], 0, 0, 0);
      acc3[2][pt] = __builtin_amdgcn_mfma_f32_16x16x32_f16(af2, bf, acc3[2][pt], 0, 0, 0);
    }
  }
  /* ---- epilogue: bias+relu, fallback capture, per-channel max over 64 points ---- */
  {
    int fl[4], vld[4];
    #pragma unroll
    for (int pt = 0; pt < 4; ++pt) {
      fl[pt]  = flag_s[pt * 16 + pcol];
      vld[pt] = (pt * 16 + pcol) < len;
    }
    #pragma unroll
    for (int c = 0; c < 3; ++c) {
      int ct = wid * 3 + c;
      float4 bb = *(const float4*)&b3v[ct * 16 + g * 4];
      float bj[4] = {bb.x, bb.y, bb.z, bb.w};
      #pragma unroll
      for (int j = 0; j < 4; ++j) {
        float vm = 0.f;
        #pragma unroll
        for (int pt = 0; pt < 4; ++pt) {
          float v = fmaxf(acc3[c][pt][j] + bj[j], 0.f);
          if (fl[pt]) fallback[b * 384 + ct * 16 + g * 4 + j] = v;
          if (!vld[pt]) v = 0.f;
          vm = fmaxf(vm, v);
        }
        vm = fmaxf(vm, __shfl_xor(vm, 1));
        vm = fmaxf(vm, __shfl_xor(vm, 2));
        vm = fmaxf(vm, __shfl_xor(vm, 4));
        vm = fmaxf(vm, __shfl_xor(vm, 8));
        if (pcol == 0)
          atomicMax((int*)&node_max[(size_t)seg * 384 + ct * 16 + g * 4 + j],
                    __float_as_int(vm));
      }
    }
  }
}

/* ---------------- kernel D: SOM-neighborhood KNN module -------------------------------- */
__global__ __launch_bounds__(256) void kD(
    const float* __restrict__ mean, const float* __restrict__ node_max,
    const float* __restrict__ fallback, const int* __restrict__ cnt,
    const int* __restrict__ knn_I,
    const float* __restrict__ w0T, const float* __restrict__ b0v,
    const float* __restrict__ w1T, const float* __restrict__ b1v,
    float* __restrict__ knn_feat, float* __restrict__ center_out) {
  __shared__ float aug_s[9][388];
  __shared__ float g1_s[9][512];
  __shared__ int nb_s[9];
  __shared__ float ctr_s[3];
  int seg = blockIdx.x;
  int b = seg >> 6;
  int t = threadIdx.x;
  if (t < 9) nb_s[t] = knn_I[seg * 9 + t];
  __syncthreads();
  if (t < 27) { int kk = t / 3, c = t - kk * 3; aug_s[kk][c] = mean[(b * 64 + nb_s[kk]) * 3 + c]; }
  __syncthreads();
  if (t < 3) {
    float s = 0.f;
    #pragma unroll
    for (int kk = 0; kk < 9; ++kk) s += aug_s[kk][t];
    s *= (1.f / 9.f);
    ctr_s[t] = s;
    center_out[seg * 3 + t] = s;
  }
  __syncthreads();
  if (t < 27) { int kk = t / 3, c = t - kk * 3; aug_s[kk][c] -= ctr_s[c]; }
  for (int kk = 0; kk < 9; ++kk) {
    int nb = nb_s[kk];
    const float* src = (cnt[b * 64 + nb] > 0) ? (node_max + (size_t)(b * 64 + nb) * 384)
                                              : (fallback + (size_t)b * 384);
    for (int i = t; i < 384; i += 256) aug_s[kk][3 + i] = src[i];
  }
  if (t < 9) aug_s[t][387] = 0.f;
  __syncthreads();
  {
    float acc0[9], acc1[9];
    float bb0 = b0v[t], bb1 = b0v[t + 256];
    #pragma unroll
    for (int kk = 0; kk < 9; ++kk) { acc0[kk] = bb0; acc1[kk] = bb1; }
    for (int i = 0; i < 388; i += 2) {
      float wA0 = w0T[i * 512 + t],        wB0 = w0T[i * 512 + t + 256];
      float wA1 = w0T[(i + 1) * 512 + t],  wB1 = w0T[(i + 1) * 512 + t + 256];
      #pragma unroll
      for (int kk = 0; kk < 9; ++kk) {
        float2 a = *(const float2*)&aug_s[kk][i];
        acc0[kk] = fmaf(wA0, a.x, acc0[kk]); acc1[kk] = fmaf(wB0, a.x, acc1[kk]);
        acc0[kk] = fmaf(wA1, a.y, acc0[kk]); acc1[kk] = fmaf(wB1, a.y, acc1[kk]);
      }
    }
    #pragma unroll
    for (int kk = 0; kk < 9; ++kk) {
      g1_s[kk][t]       = fmaxf(acc0[kk], 0.f);
      g1_s[kk][t + 256] = fmaxf(acc1[kk], 0.f);
    }
  }
  __syncthreads();
  {
    float acc0[9], acc1[9];
    float bb0 = b1v[t], bb1 = b1v[t + 256];
    #pragma unroll
    for (int kk = 0; kk < 9; ++kk) { acc0[kk] = bb0; acc1[kk] = bb1; }
    for (int i = 0; i < 512; i += 2) {
      float wA0 = w1T[i * 512 + t],        wB0 = w1T[i * 512 + t + 256];
      float wA1 = w1T[(i + 1) * 512 + t],  wB1 = w1T[(i + 1) * 512 + t + 256];
      #pragma unroll
      for (int kk = 0; kk < 9; ++kk) {
        float2 a = *(const float2*)&g1_s[kk][i];
        acc0[kk] = fmaf(wA0, a.x, acc0[kk]); acc1[kk] = fmaf(wB0, a.x, acc1[kk]);
        acc0[kk] = fmaf(wA1, a.y, acc0[kk]); acc1[kk] = fmaf(wB1, a.y, acc1[kk]);
      }
    }
    float m0 = acc0[0], m1 = acc1[0];
    #pragma unroll
    for (int kk = 1; kk < 9; ++kk) { m0 = fmaxf(m0, acc0[kk]); m1 = fmaxf(m1, acc1[kk]); }
    knn_feat[(size_t)seg * 512 + t]       = fmaxf(m0, 0.f);
    knn_feat[(size_t)seg * 512 + t + 256] = fmaxf(m1, 0.f);
  }
}

/* ---------------- kernel E: final PointNet + global max pool --------------------------- */
__global__ __launch_bounds__(256) void kE(
    const float* __restrict__ center, const float* __restrict__ knn_feat,
    const float* __restrict__ w0T, const float* __restrict__ b0v,
    const float* __restrict__ w1T, const float* __restrict__ b1v,
    float* __restrict__ out) {
  __shared__ float in_s[8][516];
  __shared__ float mid_s[8][772];
  int blk = blockIdx.x;
  int t = threadIdx.x;
  int col0 = blk * 8;
  int b = col0 >> 6;
  for (int c8 = 0; c8 < 8; ++c8) {
    int seg = col0 + c8;
    if (t < 3) in_s[c8][t] = center[seg * 3 + t];
    for (int i = t; i < 512; i += 256) in_s[c8][3 + i] = knn_feat[(size_t)seg * 512 + i];
    if (t == 0) in_s[c8][515] = 0.f;
  }
  __syncthreads();
  {
    float acc[3][8];
    #pragma unroll
    for (int q = 0; q < 3; ++q) {
      float bb = b0v[t + 256 * q];
      #pragma unroll
      for (int c8 = 0; c8 < 8; ++c8) acc[q][c8] = bb;
    }
    for (int i = 0; i < 516; i += 2) {
      float w00 = w0T[i * 768 + t], w01 = w0T[i * 768 + t + 256], w02 = w0T[i * 768 + t + 512];
      float w10 = w0T[(i + 1) * 768 + t], w11 = w0T[(i + 1) * 768 + t + 256], w12 = w0T[(i + 1) * 768 + t + 512];
      #pragma unroll
      for (int c8 = 0; c8 < 8; ++c8) {
        float2 a = *(const float2*)&in_s[c8][i];
        acc[0][c8] = fmaf(w00, a.x, acc[0][c8]); acc[0][c8] = fmaf(w10, a.y, acc[0][c8]);
        acc[1][c8] = fmaf(w01, a.x, acc[1][c8]); acc[1][c8] = fmaf(w11, a.y, acc[1][c8]);
        acc[2][c8] = fmaf(w02, a.x, acc[2][c8]); acc[2][c8] = fmaf(w12, a.y, acc[2][c8]);
      }
    }
    #pragma unroll
    for (int q = 0; q < 3; ++q)
      #pragma unroll
      for (int c8 = 0; c8 < 8; ++c8)
        mid_s[c8][t + 256 * q] = fmaxf(acc[q][c8], 0.f);
  }
  __syncthreads();
  {
    float acc[4][8];
    #pragma unroll
    for (int q = 0; q < 4; ++q) {
      float bb = b1v[t + 256 * q];
      #pragma unroll
      for (int c8 = 0; c8 < 8; ++c8) acc[q][c8] = bb;
    }
    for (int i = 0; i < 768; i += 2) {
      float wq0[4], wq1[4];
      #pragma unroll
      for (int q = 0; q < 4; ++q) {
        wq0[q] = w1T[i * 1024 + t + 256 * q];
        wq1[q] = w1T[(i + 1) * 1024 + t + 256 * q];
      }
      #pragma unroll
      for (int c8 = 0; c8 < 8; ++c8) {
        float2 a = *(const float2*)&mid_s[c8][i];
        #pragma unroll
        for (int q = 0; q < 4; ++q) {
          acc[q][c8] = fmaf(wq0[q], a.x, acc[q][c8]);
          acc[q][c8] = fmaf(wq1[q], a.y, acc[q][c8]);
        }
      }
    }
    #pragma unroll
    for (int q = 0; q < 4; ++q) {
      float v = acc[q][0];
      #pragma unroll
      for (int c8 = 1; c8 < 8; ++c8) v = fmaxf(v, acc[q][c8]);
      v = fmaxf(v, 0.f);
      atomicMax((int*)&out[b * 1024 + t + 256 * q], __float_as_int(v));
    }
  }
}

/* ---------------- launcher -------------------------------------------------------------- */
extern "C" void kernel_launch(void* const* d_in, const int* in_sizes, int n_in,
                              void* d_out, int out_size, void* d_ws, size_t ws_size,
                              hipStream_t stream) {
  const float* x      = (const float*)d_in[0];
  const float* sn     = (const float*)d_in[1];
  const float* node   = (const float*)d_in[2];
  const int*   knn_I  = (const int*)d_in[3];
  const float* pr_w0  = (const float*)d_in[4];
  const float* pr_b0  = (const float*)d_in[5];
  const float* pr_w1  = (const float*)d_in[6];
  const float* pr_b1  = (const float*)d_in[7];
  const float* pr_w2  = (const float*)d_in[8];
  const float* pr_b2  = (const float*)d_in[9];
  const float* pr_w3  = (const float*)d_in[10];
  const float* pr_b3  = (const float*)d_in[11];
  const float* knn_w0 = (const float*)d_in[12];
  const float* knn_b0 = (const float*)d_in[13];
  const float* knn_w1 = (const float*)d_in[14];
  const float* knn_b1 = (const float*)d_in[15];
  const float* fin_w0 = (const float*)d_in[16];
  const float* fin_b0 = (const float*)d_in[17];
  const float* fin_w1 = (const float*)d_in[18];
  const float* fin_b1 = (const float*)d_in[19];
  float* out = (float*)d_out;
  char* ws = (char*)d_ws;

  int*   idx_buf   = (int*)(ws + OFF_IDX);
  int*   perm      = (int*)(ws + OFF_PERM);
  int*   cnt       = (int*)(ws + OFF_CNT);
  float* sums      = (float*)(ws + OFF_SUMS);
  int*   offs      = (int*)(ws + OFF_OFFS);
  int*   cursor    = (int*)(ws + OFF_CURSOR);
  int*   nchunks   = (int*)(ws + OFF_NCHUNK);
  int*   chunk_tab = (int*)(ws + OFF_CHUNKTAB);
  float* mean      = (float*)(ws + OFF_MEAN);
  float* fallback  = (float*)(ws + OFF_FALLBACK);
  float* node_max  = (float*)(ws + OFF_NODEMAX);
  float* centerb   = (float*)(ws + OFF_CENTER);
  float* knn_feat  = (float*)(ws + OFF_KNNFEAT);
  float* w0T_knn   = (float*)(ws + OFF_W0T_KNN);
  float* w1T_knn   = (float*)(ws + OFF_W1T_KNN);
  float* w0T_fin   = (float*)(ws + OFF_W0T_FIN);
  float* w1T_fin   = (float*)(ws + OFF_W1T_FIN);
  f16*   w1p       = (f16*)(ws + OFF_W1P);
  f16*   w2p       = (f16*)(ws + OFF_W2P);
  f16*   w3p       = (f16*)(ws + OFF_W3P);

  hipMemsetAsync(ws + OFF_CNT, 0, 8192, stream);                 /* cnt + sums */
  hipMemsetAsync(ws + OFF_NODEMAX, 0, (size_t)SEGS * 384 * 4, stream);
  hipMemsetAsync(d_out, 0, (size_t)out_size * 4, stream);

  kW<<<7060, 256, 0, stream>>>(knn_w0, knn_w1, fin_w0, fin_w1, pr_w1, pr_w2, pr_w3,
                               w0T_knn, w1T_knn, w0T_fin, w1T_fin, w1p, w2p, w3p);

  dim3 gA(NQ / 256, BQ);
  kA<<<gA, 256, 0, stream>>>(x, node, idx_buf, cnt, sums);
  kB<<<1, 256, 0, stream>>>(cnt, sums, offs, cursor, nchunks, chunk_tab, mean);
  kA2<<<gA, 256, 0, stream>>>(idx_buf, cursor, perm);
  kC<<<MAXCHUNK, 512, 0, stream>>>(x, sn, mean, perm, chunk_tab, nchunks,
                                   pr_w0, pr_b0, w1p, pr_b1, w2p, pr_b2, w3p, pr_b3,
                                   node_max, fallback);
  kD<<<SEGS, 256, 0, stream>>>(mean, node_max, fallback, cnt, knn_I,
                               w0T_knn, knn_b0, w1T_knn, knn_b1, knn_feat, centerb);
  kE<<<64, 256, 0, stream>>>(centerb, knn_feat, w0T_fin, fin_b0, w1T_fin, fin_b1, out);
}

// Round 4
// 291.088 us; speedup vs baseline: 7.8852x; 2.4657x over previous
//
#include <hip/hip_runtime.h>

typedef unsigned short u16;
typedef unsigned int   u32;
typedef _Float16 f16;
typedef _Float16 f16x8 __attribute__((ext_vector_type(8)));
typedef _Float16 f16x4 __attribute__((ext_vector_type(4)));
typedef float    f32x4 __attribute__((ext_vector_type(4)));

#define BQ 8
#define NQ 8192
#define MQ 64
#define SEGS (BQ*MQ)        /* 512 */
#define MAXCHUNK 3584
#define KBA 10              /* k-blocks in concat(h0,h2) = 320/32 */
#define NCOLS_D 4608        /* 9*512 cols for KNN module, layout [kk][seg] */

/* ---- workspace layout (bytes) ---- */
#define OFF_IDX      (size_t)0         /* int[B*N*3]       786432 */
#define OFF_PERM     (size_t)786432    /* int[196608]      786432 */
#define OFF_CNT      (size_t)1572864   /* int[512]           2048 */
#define OFF_SUMS     (size_t)1574912   /* float[1536]        6144 */
#define OFF_OFFS     (size_t)1581056   /* int[513]      pad  2304 */
#define OFF_CURSOR   (size_t)1583360   /* int[512]           2048 */
#define OFF_NCHUNK   (size_t)1585408   /* int[64]             256 */
#define OFF_CHUNKTAB (size_t)1585664   /* int[2*3584]       28672 */
#define OFF_MEAN     (size_t)1614336   /* float[1536]        6144 */
#define OFF_FALLBACK (size_t)1620480   /* float[8*384]      12288 */
#define OFF_NODEMAX  (size_t)1632768   /* float[512*384]   786432 */
#define OFF_CENTER   (size_t)2419200   /* float[512*3]       6144 */
#define OFF_W1P      (size_t)2425344   /* f16 frag 128x64    16384 */
#define OFF_W2P      (size_t)2441728   /* f16 frag 256x128   65536 */
#define OFF_W3P      (size_t)2507264   /* f16 frag 384x320  245760 */
#define OFF_KNW0P    (size_t)2753024   /* f16 frag 512x416  425984 */
#define OFF_KNW1P    (size_t)3179008   /* f16 frag 512x512  524288 */
#define OFF_FINW0P   (size_t)3703296   /* f16 frag 768x544  835584 */
#define OFF_FINW1P   (size_t)4538880   /* f16 frag 1024x768 1572864 */
#define OFF_AUG      (size_t)6111744   /* f16 Bfrag 4608x416 3833856 */
#define OFF_MID1     (size_t)9945600   /* f16 Bfrag 4608x512 4718592 */
#define OFF_GBUF     (size_t)14664192  /* f16 [col][512]     4718592 */
#define OFF_KEIN     (size_t)19382784  /* f16 Bfrag 512x544   557056 */
#define OFF_MIDE     (size_t)19939840  /* f16 Bfrag 512x768   786432 */

/* ---------------- kernel W: all weight packs (A-fragment layout, f16) ------------------- */
/* out[((rt*KB+kb)*64+l)*8+e] = W[rt*16+(l&15)][colmap(kb*32+(l>>4)*8+e)]
   NF < 0 : colmap(c) = c (c<K) else zero-pad.
   NF >= 0: permuted rows [feat NF, coords 3, pad]: colmap(c) = 3+c (c<NF), c-NF (c<NF+3), pad. */
__device__ __forceinline__ void wpack(const float* __restrict__ W, f16* __restrict__ out,
                                      int K, int KB, int NF, int idx) {
  int e  = idx & 7;
  int l  = (idx >> 3) & 63;
  int kb = (idx >> 9) % KB;
  int rt = idx / (KB << 9);
  int row = rt * 16 + (l & 15);
  int c = kb * 32 + ((l >> 4) << 3) + e;
  int oc;
  if (NF < 0) oc = (c < K) ? c : -1;
  else        oc = (c < NF) ? (3 + c) : ((c < NF + 3) ? (c - NF) : -1);
  out[idx] = (oc >= 0) ? (f16)W[row * K + oc] : (f16)0.f;
}
__global__ __launch_bounds__(256) void kW(
    const float* pr_w1, const float* pr_w2, const float* pr_w3,
    const float* knn_w0, const float* knn_w1, const float* fin_w0, const float* fin_w1,
    f16* w1p, f16* w2p, f16* w3p, f16* knw0p, f16* knw1p, f16* finw0p, f16* finw1p) {
  int blk = blockIdx.x;
  int t = threadIdx.x;
  if (blk < 32)        wpack(pr_w1,  w1p,   64,  2, -1, blk * 256 + t);
  else if (blk < 160)  wpack(pr_w2,  w2p,  128,  4, -1, (blk - 32) * 256 + t);
  else if (blk < 640)  wpack(pr_w3,  w3p,  320, 10, -1, (blk - 160) * 256 + t);
  else if (blk < 1472) wpack(knn_w0, knw0p, 387, 13, 384, (blk - 640) * 256 + t);
  else if (blk < 2496) wpack(knn_w1, knw1p, 512, 16, -1, (blk - 1472) * 256 + t);
  else if (blk < 4128) wpack(fin_w0, finw0p, 515, 17, 512, (blk - 2496) * 256 + t);
  else                 wpack(fin_w1, finw1p, 768, 24, -1, (blk - 4128) * 256 + t);
}

/* ---------------- kernel A: top-3 nearest SOM nodes + LDS-binned count/sum ------------- */
__global__ __launch_bounds__(256) void kA(const float* __restrict__ x, const float* __restrict__ node,
                                          int* __restrict__ idx_buf, int* __restrict__ cnt,
                                          float* __restrict__ sums) {
#pragma clang fp contract(off)
  __shared__ float ns[3][64];
  __shared__ int cbin[64];
  __shared__ float sbin[3][64];
  int b = blockIdx.y;
  int t = threadIdx.x;
  if (t < 192) { int c = t >> 6, m = t & 63; ns[c][m] = node[(b * 3 + c) * 64 + m]; }
  if (t < 64) { cbin[t] = 0; sbin[0][t] = 0.f; sbin[1][t] = 0.f; sbin[2][t] = 0.f; }
  __syncthreads();
  int n = blockIdx.x * 256 + t;
  float x0 = x[(b * 3 + 0) * NQ + n];
  float x1 = x[(b * 3 + 1) * NQ + n];
  float x2 = x[(b * 3 + 2) * NQ + n];
  float d0 = 3.4e38f, d1 = 3.4e38f, d2 = 3.4e38f;
  int i0 = 0, i1 = 0, i2 = 0;
  for (int m = 0; m < 64; ++m) {
    float da = ns[0][m] - x0;
    float db = ns[1][m] - x1;
    float dc = ns[2][m] - x2;
    float d = da * da + db * db + dc * dc;
    if (d < d0)      { d2 = d1; i2 = i1; d1 = d0; i1 = i0; d0 = d; i0 = m; }
    else if (d < d1) { d2 = d1; i2 = i1; d1 = d;  i1 = m; }
    else if (d < d2) { d2 = d;  i2 = m; }
  }
  int base = (b * NQ + n) * 3;
  idx_buf[base + 0] = i0; idx_buf[base + 1] = i1; idx_buf[base + 2] = i2;
  int ms[3] = {i0, i1, i2};
  #pragma unroll
  for (int j = 0; j < 3; ++j) {
    int m = ms[j];
    atomicAdd(&cbin[m], 1);
    atomicAdd(&sbin[0][m], x0);
    atomicAdd(&sbin[1][m], x1);
    atomicAdd(&sbin[2][m], x2);
  }
  __syncthreads();
  if (t < 64 && cbin[t] > 0) {
    atomicAdd(&cnt[b * 64 + t], cbin[t]);
    atomicAdd(&sums[(b * 64 + t) * 3 + 0], sbin[0][t]);
    atomicAdd(&sums[(b * 64 + t) * 3 + 1], sbin[1][t]);
    atomicAdd(&sums[(b * 64 + t) * 3 + 2], sbin[2][t]);
  }
}

/* ---------------- kernel B: parallel scans, chunk table, cluster means ------------------ */
__global__ __launch_bounds__(256) void kB(const int* __restrict__ cnt, const float* __restrict__ sums,
                                          int* __restrict__ offs, int* __restrict__ cursor,
                                          int* __restrict__ nchunks, int* __restrict__ chunk_tab,
                                          float* __restrict__ mean) {
  __shared__ int sps[256], spc[256];
  int t = threadIdx.x;
  int c0 = cnt[2 * t], c1 = cnt[2 * t + 1];
  sps[t] = c0 + c1;
  spc[t] = ((c0 + 63) >> 6) + ((c1 + 63) >> 6);
  __syncthreads();
  for (int d = 1; d < 256; d <<= 1) {
    int a = 0, q = 0;
    if (t >= d) { a = sps[t - d]; q = spc[t - d]; }
    __syncthreads();
    if (t >= d) { sps[t] += a; spc[t] += q; }
    __syncthreads();
  }
  int pbase = t ? sps[t - 1] : 0;
  int cbase = t ? spc[t - 1] : 0;
  offs[2 * t] = pbase;        offs[2 * t + 1] = pbase + c0;
  cursor[2 * t] = pbase;      cursor[2 * t + 1] = pbase + c0;
  if (t == 255) { offs[512] = sps[255]; nchunks[0] = spc[255]; }
  int st = pbase, ci = cbase, s = 2 * t, c = c0;
  #pragma unroll
  for (int rep = 0; rep < 2; ++rep) {
    while (c > 0) {
      int l = c > 64 ? 64 : c;
      chunk_tab[2 * ci] = (s << 16) | l;
      chunk_tab[2 * ci + 1] = st;
      st += l; c -= l; ++ci;
    }
    s = 2 * t + 1; c = c1; st = pbase + c0;
  }
  for (int i = t; i < SEGS * 3; i += 256) mean[i] = sums[i] / ((float)cnt[i / 3] + 1e-5f);
}

/* ---------------- kernel A2: bucket points by (b,node) ---------------------------------- */
__global__ __launch_bounds__(256) void kA2(const int* __restrict__ idx_buf, int* __restrict__ cursor,
                                           int* __restrict__ perm) {
  int b = blockIdx.y;
  int n = blockIdx.x * 256 + threadIdx.x;
  int base = (b * NQ + n) * 3;
  #pragma unroll
  for (int j = 0; j < 3; ++j) {
    int m = idx_buf[base + j];
    int pos = atomicAdd(&cursor[b * 64 + m], 1);
    perm[pos] = (b << 21) | (n << 8) | (j << 6) | m;
  }
}

/* ---------------- kernel Ctr: SOM-neighborhood centers --------------------------------- */
__global__ __launch_bounds__(256) void kCtr(const float* __restrict__ mean,
                                            const int* __restrict__ knn_I,
                                            float* __restrict__ centerb) {
  int seg = blockIdx.x * 256 + threadIdx.x;
  if (seg >= SEGS) return;
  int b = seg >> 6;
  float s0 = 0, s1 = 0, s2 = 0;
  for (int kk = 0; kk < 9; ++kk) {
    int nb = knn_I[seg * 9 + kk];
    s0 += mean[(b * 64 + nb) * 3 + 0];
    s1 += mean[(b * 64 + nb) * 3 + 1];
    s2 += mean[(b * 64 + nb) * 3 + 2];
  }
  centerb[seg * 3 + 0] = s0 * (1.f / 9.f);
  centerb[seg * 3 + 1] = s1 * (1.f / 9.f);
  centerb[seg * 3 + 2] = s2 * (1.f / 9.f);
}

/* ---------------- kernel C: fused MFMA PointResNet + per-node scatter-max --------------- */
__global__ __launch_bounds__(512) void kC(
    const float* __restrict__ x, const float* __restrict__ sn,
    const float* __restrict__ mean, const int* __restrict__ perm,
    const int* __restrict__ chunk_tab, const int* __restrict__ nchunks,
    const float* __restrict__ w0, const float* __restrict__ b0v,
    const f16* __restrict__ w1p, const float* __restrict__ b1v,
    const f16* __restrict__ w2p, const float* __restrict__ b2v,
    const f16* __restrict__ w3p, const float* __restrict__ b3v,
    float* __restrict__ node_max, float* __restrict__ fallback) {
  __shared__ __align__(16) f16 bufA[4 * KBA * 64 * 8];
  __shared__ __align__(16) f16 bufH1[4 * 4 * 64 * 8];
  __shared__ float in_s[6][64];
  __shared__ int flag_s[64];
  int blk = blockIdx.x;
  if (blk >= nchunks[0]) return;
  int e0    = chunk_tab[2 * blk];
  int start = chunk_tab[2 * blk + 1];
  int seg = e0 >> 16, len = e0 & 0xffff;
  int b = seg >> 6;
  int tid = threadIdx.x;
  if (tid < 64) {
    float v0 = 0, v1 = 0, v2 = 0, v3 = 0, v4 = 0, v5 = 0;
    int fl = 0;
    if (tid < len) {
      int rec = perm[start + tid];
      int n = (rec >> 8) & 0x1fff;
      int j = (rec >> 6) & 3;
      const float* xb = x  + (size_t)b * 3 * NQ;
      const float* sb = sn + (size_t)b * 3 * NQ;
      v0 = xb[n]          - mean[seg * 3 + 0];
      v1 = xb[NQ + n]     - mean[seg * 3 + 1];
      v2 = xb[2 * NQ + n] - mean[seg * 3 + 2];
      v3 = sb[n]; v4 = sb[NQ + n]; v5 = sb[2 * NQ + n];
      fl = (n == 0 && j == 0) ? 1 : 0;
    }
    in_s[0][tid] = v0; in_s[1][tid] = v1; in_s[2][tid] = v2;
    in_s[3][tid] = v3; in_s[4][tid] = v4; in_s[5][tid] = v5;
    flag_s[tid] = fl;
  }
  __syncthreads();
  int wid  = __builtin_amdgcn_readfirstlane(tid >> 6);
  int lane = tid & 63;
  int pcol = lane & 15;
  int g    = lane >> 4;

  /* L1 scalar 6->64 */
  {
    float a0 = in_s[0][lane], a1 = in_s[1][lane], a2 = in_s[2][lane];
    float a3 = in_s[3][lane], a4 = in_s[4][lane], a5 = in_s[5][lane];
    f16x8 v;
    #pragma unroll
    for (int i = 0; i < 8; ++i) {
      const float* wr = w0 + (wid * 8 + i) * 6;
      float s = b0v[wid * 8 + i];
      s = fmaf(wr[0], a0, s); s = fmaf(wr[1], a1, s); s = fmaf(wr[2], a2, s);
      s = fmaf(wr[3], a3, s); s = fmaf(wr[4], a4, s); s = fmaf(wr[5], a5, s);
      v[i] = (f16)fmaxf(s, 0.f);
    }
    int kb = wid >> 2, q = wid & 3;
    *(f16x8*)&bufA[(((lane >> 4) * KBA + kb) * 64 + pcol + 16 * q) * 8] = v;
  }
  __syncthreads();

  /* L2 MFMA 64->128 */
  f32x4 acc1[4] = {};
  #pragma unroll
  for (int kb = 0; kb < 2; ++kb) {
    f16x8 af = *(const f16x8*)(w1p + (size_t)((wid * 2 + kb) * 64 + lane) * 8);
    #pragma unroll
    for (int pt = 0; pt < 4; ++pt) {
      f16x8 bf = *(const f16x8*)&bufA[((pt * KBA + kb) * 64 + lane) * 8];
      acc1[pt] = __builtin_amdgcn_mfma_f32_16x16x32_f16(af, bf, acc1[pt], 0, 0, 0);
    }
  }
  {
    float4 bb = *(const float4*)&b1v[wid * 16 + g * 4];
    int kbo = wid >> 1;
    int q   = ((wid & 1) << 1) + (g >> 1);
    int ee  = (g & 1) * 4;
    #pragma unroll
    for (int pt = 0; pt < 4; ++pt) {
      f16x4 v;
      v[0] = (f16)fmaxf(acc1[pt][0] + bb.x, 0.f);
      v[1] = (f16)fmaxf(acc1[pt][1] + bb.y, 0.f);
      v[2] = (f16)fmaxf(acc1[pt][2] + bb.z, 0.f);
      v[3] = (f16)fmaxf(acc1[pt][3] + bb.w, 0.f);
      *(f16x4*)&bufH1[((pt * 4 + kbo) * 64 + pcol + 16 * q) * 8 + ee] = v;
    }
  }
  __syncthreads();

  /* L3 MFMA 128->256 */
  f32x4 acc2[2][4] = {};
  #pragma unroll
  for (int kb = 0; kb < 4; ++kb) {
    f16x8 af0 = *(const f16x8*)(w2p + (size_t)(((wid * 2 + 0) * 4 + kb) * 64 + lane) * 8);
    f16x8 af1 = *(const f16x8*)(w2p + (size_t)(((wid * 2 + 1) * 4 + kb) * 64 + lane) * 8);
    #pragma unroll
    for (int pt = 0; pt < 4; ++pt) {
      f16x8 bf = *(const f16x8*)&bufH1[((pt * 4 + kb) * 64 + lane) * 8];
      acc2[0][pt] = __builtin_amdgcn_mfma_f32_16x16x32_f16(af0, bf, acc2[0][pt], 0, 0, 0);
      acc2[1][pt] = __builtin_amdgcn_mfma_f32_16x16x32_f16(af1, bf, acc2[1][pt], 0, 0, 0);
    }
  }
  {
    int kbo = 2 + wid;
    #pragma unroll
    for (int s = 0; s < 2; ++s) {
      float4 bb = *(const float4*)&b2v[(wid * 2 + s) * 16 + g * 4];
      int q  = 2 * s + (g >> 1);
      int ee = (g & 1) * 4;
      #pragma unroll
      for (int pt = 0; pt < 4; ++pt) {
        f16x4 v;
        v[0] = (f16)fmaxf(acc2[s][pt][0] + bb.x, 0.f);
        v[1] = (f16)fmaxf(acc2[s][pt][1] + bb.y, 0.f);
        v[2] = (f16)fmaxf(acc2[s][pt][2] + bb.z, 0.f);
        v[3] = (f16)fmaxf(acc2[s][pt][3] + bb.w, 0.f);
        *(f16x4*)&bufA[((pt * KBA + kbo) * 64 + pcol + 16 * q) * 8 + ee] = v;
      }
    }
  }
  __syncthreads();

  /* L4 MFMA 320->384 */
  f32x4 acc3[3][4] = {};
  #pragma unroll
  for (int kb = 0; kb < KBA; ++kb) {
    f16x8 af0 = *(const f16x8*)(w3p + (size_t)(((wid * 3 + 0) * KBA + kb) * 64 + lane) * 8);
    f16x8 af1 = *(const f16x8*)(w3p + (size_t)(((wid * 3 + 1) * KBA + kb) * 64 + lane) * 8);
    f16x8 af2 = *(const f16x8*)(w3p + (size_t)(((wid * 3 + 2) * KBA + kb) * 64 + lane) * 8);
    #pragma unroll
    for (int pt = 0; pt < 4; ++pt) {
      f16x8 bf = *(const f16x8*)&bufA[((pt * KBA + kb) * 64 + lane) * 8];
      acc3[0][pt] = __builtin_amdgcn_mfma_f32_16x16x32_f16(af0, bf, acc3[0][pt], 0, 0, 0);
      acc3[1][pt] = __builtin_amdgcn_mfma_f32_16x16x32_f16(af1, bf, acc3[1][pt], 0, 0, 0);
      acc3[2][pt] = __builtin_amdgcn_mfma_f32_16x16x32_f16(af2, bf, acc3[2][pt], 0, 0, 0);
    }
  }
  {
    int fl[4], vld[4];
    #pragma unroll
    for (int pt = 0; pt < 4; ++pt) {
      fl[pt]  = flag_s[pt * 16 + pcol];
      vld[pt] = (pt * 16 + pcol) < len;
    }
    #pragma unroll
    for (int c = 0; c < 3; ++c) {
      int ct = wid * 3 + c;
      float4 bb = *(const float4*)&b3v[ct * 16 + g * 4];
      float bj[4] = {bb.x, bb.y, bb.z, bb.w};
      #pragma unroll
      for (int j = 0; j < 4; ++j) {
        float vm = 0.f;
        #pragma unroll
        for (int pt = 0; pt < 4; ++pt) {
          float v = fmaxf(acc3[c][pt][j] + bj[j], 0.f);
          if (fl[pt]) fallback[b * 384 + ct * 16 + g * 4 + j] = v;
          if (!vld[pt]) v = 0.f;
          vm = fmaxf(vm, v);
        }
        vm = fmaxf(vm, __shfl_xor(vm, 1));
        vm = fmaxf(vm, __shfl_xor(vm, 2));
        vm = fmaxf(vm, __shfl_xor(vm, 4));
        vm = fmaxf(vm, __shfl_xor(vm, 8));
        if (pcol == 0)
          atomicMax((int*)&node_max[(size_t)seg * 384 + ct * 16 + g * 4 + j],
                    __float_as_int(vm));
      }
    }
  }
}

/* ---------------- kernel Dg: gather + pack KNN input to B-fragments -------------------- */
/* AUG rows (permuted): k 0..383 = feat, k 384..386 = coord-center, k 387..415 = 0 */
__global__ __launch_bounds__(256) void kDg(
    const float* __restrict__ mean, const float* __restrict__ node_max,
    const float* __restrict__ fallback, const int* __restrict__ cnt,
    const int* __restrict__ knn_I, const float* __restrict__ centerb,
    f16* __restrict__ augP) {
  int idx = blockIdx.x * 256 + threadIdx.x;
  if (idx < NCOLS_D * 48) {
    int col = idx / 48;
    int rg  = idx - col * 48;
    int kk = col >> 9, seg = col & 511, b = seg >> 6;
    int nb = knn_I[seg * 9 + kk];
    const float* src = (cnt[b * 64 + nb] > 0) ? (node_max + (size_t)(b * 64 + nb) * 384)
                                              : (fallback + (size_t)b * 384);
    int r = rg * 8;
    f16x8 v;
    #pragma unroll
    for (int e = 0; e < 8; ++e) v[e] = (f16)src[r + e];
    int ct = col >> 4, pc = col & 15;
    int kb = r >> 5, ks = (r >> 3) & 3;
    *(f16x8*)&augP[(size_t)((ct * 13 + kb) * 64 + pc + 16 * ks) * 8] = v;
  } else if (idx < NCOLS_D * 48 + NCOLS_D) {
    int col = idx - NCOLS_D * 48;
    int kk = col >> 9, seg = col & 511, b = seg >> 6;
    int nb = knn_I[seg * 9 + kk];
    f16x8 v = {};
    #pragma unroll
    for (int c = 0; c < 3; ++c)
      v[c] = (f16)(mean[(b * 64 + nb) * 3 + c] - centerb[seg * 3 + c]);
    int ct = col >> 4, pc = col & 15;
    *(f16x8*)&augP[(size_t)((ct * 13 + 12) * 64 + pc) * 8] = v;
    f16x8 z = {};
    #pragma unroll
    for (int ks = 1; ks < 4; ++ks)
      *(f16x8*)&augP[(size_t)((ct * 13 + 12) * 64 + pc + 16 * ks) * 8] = z;
  }
}

/* ---------------- generic MFMA GEMM: C[64r x 64c]/block, 4 waves, no LDS ---------------- */
/* MODE 0: bias+relu -> repack f16 B-frags (NKB_OUT) ; MODE 1: bias+relu -> gbuf[col][512]
   MODE 2: bias+relu -> max over 64 cols (col-block = batch) -> outF[cb*1024+row]          */
template<int NKB_IN, int NKB_OUT, int MODE>
__global__ __launch_bounds__(256) void kGemm(
    const f16* __restrict__ Ap, const f16* __restrict__ Bp,
    const float* __restrict__ bias, f16* __restrict__ outP, float* __restrict__ outF) {
  int cb = blockIdx.x;
  int rb = blockIdx.y;
  int tid = threadIdx.x;
  int wid = __builtin_amdgcn_readfirstlane(tid >> 6);
  int lane = tid & 63;
  int rt = rb * 4 + wid;
  f32x4 acc[4] = {};
  const f16* ap = Ap + (size_t)rt * NKB_IN * 512;
  const f16* bp = Bp + (size_t)cb * 4 * NKB_IN * 512;
  #pragma unroll
  for (int kb = 0; kb < NKB_IN; ++kb) {
    f16x8 af = *(const f16x8*)(ap + (size_t)(kb * 64 + lane) * 8);
    #pragma unroll
    for (int ct = 0; ct < 4; ++ct) {
      f16x8 bf = *(const f16x8*)(bp + (size_t)((ct * NKB_IN + kb) * 64 + lane) * 8);
      acc[ct] = __builtin_amdgcn_mfma_f32_16x16x32_f16(af, bf, acc[ct], 0, 0, 0);
    }
  }
  int pcol = lane & 15, g = lane >> 4;
  float4 bb = *(const float4*)&bias[rt * 16 + g * 4];
  float bj[4] = {bb.x, bb.y, bb.z, bb.w};
  if (MODE == 0) {
    int k0 = rt * 16 + g * 4;
    int kb2 = k0 >> 5, ks2 = (k0 >> 3) & 3, ee = k0 & 7;
    #pragma unroll
    for (int ct = 0; ct < 4; ++ct) {
      f16x4 v;
      #pragma unroll
      for (int j = 0; j < 4; ++j) v[j] = (f16)fmaxf(acc[ct][j] + bj[j], 0.f);
      int ctc = cb * 4 + ct;
      *(f16x4*)&outP[(size_t)((ctc * NKB_OUT + kb2) * 64 + pcol + 16 * ks2) * 8 + ee] = v;
    }
  } else if (MODE == 1) {
    #pragma unroll
    for (int ct = 0; ct < 4; ++ct) {
      f16x4 v;
      #pragma unroll
      for (int j = 0; j < 4; ++j) v[j] = (f16)fmaxf(acc[ct][j] + bj[j], 0.f);
      int col = cb * 64 + ct * 16 + pcol;
      *(f16x4*)&outP[(size_t)col * 512 + rt * 16 + g * 4] = v;
    }
  } else {
    #pragma unroll
    for (int j = 0; j < 4; ++j) {
      float v = fmaxf(acc[0][j] + bj[j], 0.f);
      #pragma unroll
      for (int ct = 1; ct < 4; ++ct) v = fmaxf(v, fmaxf(acc[ct][j] + bj[j], 0.f));
      v = fmaxf(v, __shfl_xor(v, 1));
      v = fmaxf(v, __shfl_xor(v, 2));
      v = fmaxf(v, __shfl_xor(v, 4));
      v = fmaxf(v, __shfl_xor(v, 8));
      if (pcol == 0) outF[cb * 1024 + rt * 16 + g * 4 + j] = v;
    }
  }
}

/* ---------------- kernel Dmax: max over 9 kk -> kE input pack --------------------------- */
/* kEin rows (permuted): k 0..511 = knn_feat, k 512..514 = center, k 515..543 = 0 */
__global__ __launch_bounds__(256) void kDmax(const f16* __restrict__ gbuf,
                                             const float* __restrict__ centerb,
                                             f16* __restrict__ keinP) {
  int idx = blockIdx.x * 256 + threadIdx.x;
  if (idx < SEGS * 64) {
    int seg = idx >> 6;
    int rg  = idx & 63;
    int r = rg * 8;
    float m[8] = {};
    for (int kk = 0; kk < 9; ++kk) {
      f16x8 gv = *(const f16x8*)&gbuf[(size_t)(kk * 512 + seg) * 512 + r];
      #pragma unroll
      for (int e = 0; e < 8; ++e) m[e] = fmaxf(m[e], (float)gv[e]);
    }
    f16x8 v;
    #pragma unroll
    for (int e = 0; e < 8; ++e) v[e] = (f16)m[e];
    int ct = seg >> 4, pc = seg & 15;
    int kb = r >> 5, ks = (r >> 3) & 3;
    *(f16x8*)&keinP[(size_t)((ct * 17 + kb) * 64 + pc + 16 * ks) * 8] = v;
  } else if (idx < SEGS * 64 + SEGS) {
    int seg = idx - SEGS * 64;
    f16x8 v = {};
    #pragma unroll
    for (int c = 0; c < 3; ++c) v[c] = (f16)centerb[seg * 3 + c];
    int ct = seg >> 4, pc = seg & 15;
    *(f16x8*)&keinP[(size_t)((ct * 17 + 16) * 64 + pc) * 8] = v;
    f16x8 z = {};
    #pragma unroll
    for (int ks = 1; ks < 4; ++ks)
      *(f16x8*)&keinP[(size_t)((ct * 17 + 16) * 64 + pc + 16 * ks) * 8] = z;
  }
}

/* ---------------- launcher -------------------------------------------------------------- */
extern "C" void kernel_launch(void* const* d_in, const int* in_sizes, int n_in,
                              void* d_out, int out_size, void* d_ws, size_t ws_size,
                              hipStream_t stream) {
  const float* x      = (const float*)d_in[0];
  const float* sn     = (const float*)d_in[1];
  const float* node   = (const float*)d_in[2];
  const int*   knn_I  = (const int*)d_in[3];
  const float* pr_w0  = (const float*)d_in[4];
  const float* pr_b0  = (const float*)d_in[5];
  const float* pr_w1  = (const float*)d_in[6];
  const float* pr_b1  = (const float*)d_in[7];
  const float* pr_w2  = (const float*)d_in[8];
  const float* pr_b2  = (const float*)d_in[9];
  const float* pr_w3  = (const float*)d_in[10];
  const float* pr_b3  = (const float*)d_in[11];
  const float* knn_w0 = (const float*)d_in[12];
  const float* knn_b0 = (const float*)d_in[13];
  const float* knn_w1 = (const float*)d_in[14];
  const float* knn_b1 = (const float*)d_in[15];
  const float* fin_w0 = (const float*)d_in[16];
  const float* fin_b0 = (const float*)d_in[17];
  const float* fin_w1 = (const float*)d_in[18];
  const float* fin_b1 = (const float*)d_in[19];
  float* out = (float*)d_out;
  char* ws = (char*)d_ws;

  int*   idx_buf   = (int*)(ws + OFF_IDX);
  int*   perm      = (int*)(ws + OFF_PERM);
  int*   cnt       = (int*)(ws + OFF_CNT);
  float* sums      = (float*)(ws + OFF_SUMS);
  int*   offs      = (int*)(ws + OFF_OFFS);
  int*   cursor    = (int*)(ws + OFF_CURSOR);
  int*   nchunks   = (int*)(ws + OFF_NCHUNK);
  int*   chunk_tab = (int*)(ws + OFF_CHUNKTAB);
  float* mean      = (float*)(ws + OFF_MEAN);
  float* fallback  = (float*)(ws + OFF_FALLBACK);
  float* node_max  = (float*)(ws + OFF_NODEMAX);
  float* centerb   = (float*)(ws + OFF_CENTER);
  f16*   w1p       = (f16*)(ws + OFF_W1P);
  f16*   w2p       = (f16*)(ws + OFF_W2P);
  f16*   w3p       = (f16*)(ws + OFF_W3P);
  f16*   knw0p     = (f16*)(ws + OFF_KNW0P);
  f16*   knw1p     = (f16*)(ws + OFF_KNW1P);
  f16*   finw0p    = (f16*)(ws + OFF_FINW0P);
  f16*   finw1p    = (f16*)(ws + OFF_FINW1P);
  f16*   augP      = (f16*)(ws + OFF_AUG);
  f16*   mid1P     = (f16*)(ws + OFF_MID1);
  f16*   gbuf      = (f16*)(ws + OFF_GBUF);
  f16*   keinP     = (f16*)(ws + OFF_KEIN);
  f16*   midEP     = (f16*)(ws + OFF_MIDE);

  hipMemsetAsync(ws + OFF_CNT, 0, 8192, stream);                 /* cnt + sums */
  hipMemsetAsync(ws + OFF_NODEMAX, 0, (size_t)SEGS * 384 * 4, stream);

  kW<<<7200, 256, 0, stream>>>(pr_w1, pr_w2, pr_w3, knn_w0, knn_w1, fin_w0, fin_w1,
                               w1p, w2p, w3p, knw0p, knw1p, finw0p, finw1p);

  dim3 gA(NQ / 256, BQ);
  kA<<<gA, 256, 0, stream>>>(x, node, idx_buf, cnt, sums);
  kB<<<1, 256, 0, stream>>>(cnt, sums, offs, cursor, nchunks, chunk_tab, mean);
  kA2<<<gA, 256, 0, stream>>>(idx_buf, cursor, perm);
  kCtr<<<2, 256, 0, stream>>>(mean, knn_I, centerb);
  kC<<<MAXCHUNK, 512, 0, stream>>>(x, sn, mean, perm, chunk_tab, nchunks,
                                   pr_w0, pr_b0, w1p, pr_b1, w2p, pr_b2, w3p, pr_b3,
                                   node_max, fallback);
  kDg<<<(NCOLS_D * 48 + NCOLS_D + 255) / 256, 256, 0, stream>>>(
      mean, node_max, fallback, cnt, knn_I, centerb, augP);
  kGemm<13, 16, 0><<<dim3(72, 8), 256, 0, stream>>>(knw0p, augP, knn_b0, mid1P, nullptr);
  kGemm<16, 0, 1><<<dim3(72, 8), 256, 0, stream>>>(knw1p, mid1P, knn_b1, gbuf, nullptr);
  kDmax<<<(SEGS * 64 + SEGS + 255) / 256, 256, 0, stream>>>(gbuf, centerb, keinP);
  kGemm<17, 24, 0><<<dim3(8, 12), 256, 0, stream>>>(finw0p, keinP, fin_b0, midEP, nullptr);
  kGemm<24, 0, 2><<<dim3(8, 16), 256, 0, stream>>>(finw1p, midEP, fin_b1, nullptr, out);
}

// Round 5
// 287.367 us; speedup vs baseline: 7.9873x; 1.0129x over previous
//
#include <hip/hip_runtime.h>

typedef unsigned short u16;
typedef unsigned int   u32;
typedef _Float16 f16;
typedef _Float16 f16x8 __attribute__((ext_vector_type(8)));
typedef _Float16 f16x4 __attribute__((ext_vector_type(4)));
typedef float    f32x4 __attribute__((ext_vector_type(4)));

#define BQ 8
#define NQ 8192
#define MQ 64
#define SEGS (BQ*MQ)        /* 512 */
#define MAXCHUNK 3584
#define KBA 10              /* k-blocks in concat(h0,h2) = 320/32 */
#define NCOLS_D 4608        /* 9*512 cols for KNN module, layout [kk][seg] */
#define ROWL 520            /* padded LDS row-block stride in f16 (512+8): +4 banks/row */

/* ---- workspace layout (bytes) ---- */
#define OFF_IDX      (size_t)0
#define OFF_PERM     (size_t)786432
#define OFF_CNT      (size_t)1572864
#define OFF_SUMS     (size_t)1574912
#define OFF_OFFS     (size_t)1581056
#define OFF_CURSOR   (size_t)1583360
#define OFF_NCHUNK   (size_t)1585408
#define OFF_CHUNKTAB (size_t)1585664
#define OFF_MEAN     (size_t)1614336
#define OFF_FALLBACK (size_t)1620480
#define OFF_NODEMAX  (size_t)1632768
#define OFF_CENTER   (size_t)2419200
#define OFF_W1P      (size_t)2425344
#define OFF_W2P      (size_t)2441728
#define OFF_W3P      (size_t)2507264
#define OFF_KNW0P    (size_t)2753024
#define OFF_KNW1P    (size_t)3179008
#define OFF_FINW0P   (size_t)3703296
#define OFF_FINW1P   (size_t)4538880
#define OFF_AUG      (size_t)6111744
#define OFF_MID1     (size_t)9945600
#define OFF_GBUF     (size_t)14664192
#define OFF_KEIN     (size_t)19382784
#define OFF_MIDE     (size_t)19939840

/* ---------------- kernel W: all weight packs (A-fragment layout, f16) ------------------- */
__device__ __forceinline__ void wpack(const float* __restrict__ W, f16* __restrict__ out,
                                      int K, int KB, int NF, int idx) {
  int e  = idx & 7;
  int l  = (idx >> 3) & 63;
  int kb = (idx >> 9) % KB;
  int rt = idx / (KB << 9);
  int row = rt * 16 + (l & 15);
  int c = kb * 32 + ((l >> 4) << 3) + e;
  int oc;
  if (NF < 0) oc = (c < K) ? c : -1;
  else        oc = (c < NF) ? (3 + c) : ((c < NF + 3) ? (c - NF) : -1);
  out[idx] = (oc >= 0) ? (f16)W[row * K + oc] : (f16)0.f;
}
__global__ __launch_bounds__(256) void kW(
    const float* pr_w1, const float* pr_w2, const float* pr_w3,
    const float* knn_w0, const float* knn_w1, const float* fin_w0, const float* fin_w1,
    f16* w1p, f16* w2p, f16* w3p, f16* knw0p, f16* knw1p, f16* finw0p, f16* finw1p) {
  int blk = blockIdx.x;
  int t = threadIdx.x;
  if (blk < 32)        wpack(pr_w1,  w1p,   64,  2, -1, blk * 256 + t);
  else if (blk < 160)  wpack(pr_w2,  w2p,  128,  4, -1, (blk - 32) * 256 + t);
  else if (blk < 640)  wpack(pr_w3,  w3p,  320, 10, -1, (blk - 160) * 256 + t);
  else if (blk < 1472) wpack(knn_w0, knw0p, 387, 13, 384, (blk - 640) * 256 + t);
  else if (blk < 2496) wpack(knn_w1, knw1p, 512, 16, -1, (blk - 1472) * 256 + t);
  else if (blk < 4128) wpack(fin_w0, finw0p, 515, 17, 512, (blk - 2496) * 256 + t);
  else                 wpack(fin_w1, finw1p, 768, 24, -1, (blk - 4128) * 256 + t);
}

/* ---------------- kernel A: top-3 nearest SOM nodes + LDS-binned count/sum ------------- */
__global__ __launch_bounds__(256) void kA(const float* __restrict__ x, const float* __restrict__ node,
                                          int* __restrict__ idx_buf, int* __restrict__ cnt,
                                          float* __restrict__ sums) {
#pragma clang fp contract(off)
  __shared__ float ns[3][64];
  __shared__ int cbin[64];
  __shared__ float sbin[3][64];
  int b = blockIdx.y;
  int t = threadIdx.x;
  if (t < 192) { int c = t >> 6, m = t & 63; ns[c][m] = node[(b * 3 + c) * 64 + m]; }
  if (t < 64) { cbin[t] = 0; sbin[0][t] = 0.f; sbin[1][t] = 0.f; sbin[2][t] = 0.f; }
  __syncthreads();
  int n = blockIdx.x * 256 + t;
  float x0 = x[(b * 3 + 0) * NQ + n];
  float x1 = x[(b * 3 + 1) * NQ + n];
  float x2 = x[(b * 3 + 2) * NQ + n];
  float d0 = 3.4e38f, d1 = 3.4e38f, d2 = 3.4e38f;
  int i0 = 0, i1 = 0, i2 = 0;
  for (int m = 0; m < 64; ++m) {
    float da = ns[0][m] - x0;
    float db = ns[1][m] - x1;
    float dc = ns[2][m] - x2;
    float d = da * da + db * db + dc * dc;
    if (d < d0)      { d2 = d1; i2 = i1; d1 = d0; i1 = i0; d0 = d; i0 = m; }
    else if (d < d1) { d2 = d1; i2 = i1; d1 = d;  i1 = m; }
    else if (d < d2) { d2 = d;  i2 = m; }
  }
  int base = (b * NQ + n) * 3;
  idx_buf[base + 0] = i0; idx_buf[base + 1] = i1; idx_buf[base + 2] = i2;
  int ms[3] = {i0, i1, i2};
  #pragma unroll
  for (int j = 0; j < 3; ++j) {
    int m = ms[j];
    atomicAdd(&cbin[m], 1);
    atomicAdd(&sbin[0][m], x0);
    atomicAdd(&sbin[1][m], x1);
    atomicAdd(&sbin[2][m], x2);
  }
  __syncthreads();
  if (t < 64 && cbin[t] > 0) {
    atomicAdd(&cnt[b * 64 + t], cbin[t]);
    atomicAdd(&sums[(b * 64 + t) * 3 + 0], sbin[0][t]);
    atomicAdd(&sums[(b * 64 + t) * 3 + 1], sbin[1][t]);
    atomicAdd(&sums[(b * 64 + t) * 3 + 2], sbin[2][t]);
  }
}

/* ---------------- kernel B: scans, chunk table, cluster means, KNN centers -------------- */
__global__ __launch_bounds__(256) void kB(const int* __restrict__ cnt, const float* __restrict__ sums,
                                          int* __restrict__ offs, int* __restrict__ cursor,
                                          int* __restrict__ nchunks, int* __restrict__ chunk_tab,
                                          float* __restrict__ mean, const int* __restrict__ knn_I,
                                          float* __restrict__ centerb) {
  __shared__ int sps[256], spc[256];
  int t = threadIdx.x;
  int c0 = cnt[2 * t], c1 = cnt[2 * t + 1];
  sps[t] = c0 + c1;
  spc[t] = ((c0 + 63) >> 6) + ((c1 + 63) >> 6);
  __syncthreads();
  for (int d = 1; d < 256; d <<= 1) {
    int a = 0, q = 0;
    if (t >= d) { a = sps[t - d]; q = spc[t - d]; }
    __syncthreads();
    if (t >= d) { sps[t] += a; spc[t] += q; }
    __syncthreads();
  }
  int pbase = t ? sps[t - 1] : 0;
  int cbase = t ? spc[t - 1] : 0;
  offs[2 * t] = pbase;        offs[2 * t + 1] = pbase + c0;
  cursor[2 * t] = pbase;      cursor[2 * t + 1] = pbase + c0;
  if (t == 255) { offs[512] = sps[255]; nchunks[0] = spc[255]; }
  int st = pbase, ci = cbase, s = 2 * t, c = c0;
  #pragma unroll
  for (int rep = 0; rep < 2; ++rep) {
    while (c > 0) {
      int l = c > 64 ? 64 : c;
      chunk_tab[2 * ci] = (s << 16) | l;
      chunk_tab[2 * ci + 1] = st;
      st += l; c -= l; ++ci;
    }
    s = 2 * t + 1; c = c1; st = pbase + c0;
  }
  for (int i = t; i < SEGS * 3; i += 256) mean[i] = sums[i] / ((float)cnt[i / 3] + 1e-5f);
  for (int seg = t; seg < SEGS; seg += 256) {
    int b = seg >> 6;
    float s0 = 0.f, s1 = 0.f, s2 = 0.f;
    for (int kk = 0; kk < 9; ++kk) {
      int q = b * 64 + knn_I[seg * 9 + kk];
      float inv = 1.f / ((float)cnt[q] + 1e-5f);
      s0 += sums[q * 3 + 0] * inv;
      s1 += sums[q * 3 + 1] * inv;
      s2 += sums[q * 3 + 2] * inv;
    }
    centerb[seg * 3 + 0] = s0 * (1.f / 9.f);
    centerb[seg * 3 + 1] = s1 * (1.f / 9.f);
    centerb[seg * 3 + 2] = s2 * (1.f / 9.f);
  }
}

/* ---------------- kernel A2: bucket points by (b,node), LDS-binned cursor --------------- */
__global__ __launch_bounds__(256) void kA2(const int* __restrict__ idx_buf, int* __restrict__ cursor,
                                           int* __restrict__ perm) {
  __shared__ int loc[64];
  __shared__ int base_s[64];
  int b = blockIdx.y;
  int t = threadIdx.x;
  if (t < 64) loc[t] = 0;
  __syncthreads();
  int n = blockIdx.x * 256 + t;
  int base = (b * NQ + n) * 3;
  int m0 = idx_buf[base + 0], m1 = idx_buf[base + 1], m2 = idx_buf[base + 2];
  int l0 = atomicAdd(&loc[m0], 1);
  int l1 = atomicAdd(&loc[m1], 1);
  int l2 = atomicAdd(&loc[m2], 1);
  __syncthreads();
  if (t < 64 && loc[t] > 0) base_s[t] = atomicAdd(&cursor[b * 64 + t], loc[t]);
  __syncthreads();
  perm[base_s[m0] + l0] = (b << 21) | (n << 8) | (0 << 6) | m0;
  perm[base_s[m1] + l1] = (b << 21) | (n << 8) | (1 << 6) | m1;
  perm[base_s[m2] + l2] = (b << 21) | (n << 8) | (2 << 6) | m2;
}

/* ---------------- kernel C: persistent fused MFMA PointResNet + scatter-max ------------- */
/* 256 blocks (1/CU), 512 thr. L2+L4 weight frags held in VGPRs across the chunk loop.     */
__global__ __launch_bounds__(512, 2) void kC(
    const float* __restrict__ x, const float* __restrict__ sn,
    const float* __restrict__ mean, const int* __restrict__ perm,
    const int* __restrict__ chunk_tab, const int* __restrict__ nchunks,
    const float* __restrict__ w0, const float* __restrict__ b0v,
    const f16* __restrict__ w1p, const float* __restrict__ b1v,
    const f16* __restrict__ w2p, const float* __restrict__ b2v,
    const f16* __restrict__ w3p, const float* __restrict__ b3v,
    float* __restrict__ node_max, float* __restrict__ fallback) {
  __shared__ __align__(16) f16 bufA[4 * KBA * ROWL];   /* 41600 B */
  __shared__ __align__(16) f16 bufH1[4 * 4 * ROWL];    /* 16640 B */
  __shared__ float in_s[6][64];
  __shared__ float w0_s[448];                          /* w0[64][6] + b0[64] */
  __shared__ float b3_s[384];
  __shared__ int flag_s[64];
  __shared__ int n_s[64];
  int tid = threadIdx.x;
  int wid  = __builtin_amdgcn_readfirstlane(tid >> 6);
  int lane = tid & 63;
  int pcol = lane & 15;
  int g    = lane >> 4;

  /* one-time LDS staging of tiny constants */
  for (int i = tid; i < 384; i += 512) { w0_s[i] = w0[i]; b3_s[i] = b3v[i]; }
  if (tid < 64) w0_s[384 + tid] = b0v[tid];

  /* held weight fragments: L2 (8 VGPR) + L4 (120 VGPR) */
  f16x8 af2h[2];
  #pragma unroll
  for (int kb = 0; kb < 2; ++kb)
    af2h[kb] = *(const f16x8*)(w1p + (size_t)((wid * 2 + kb) * 64 + lane) * 8);
  f16x8 af4h[3][KBA];
  #pragma unroll
  for (int c = 0; c < 3; ++c)
    #pragma unroll
    for (int kb = 0; kb < KBA; ++kb)
      af4h[c][kb] = *(const f16x8*)(w3p + (size_t)(((wid * 3 + c) * KBA + kb) * 64 + lane) * 8);

  int nch = nchunks[0];
  for (int blk = blockIdx.x; blk < nch; blk += gridDim.x) {
    __syncthreads();   /* protect in_s/flag_s/bufA against previous iteration readers */
    int e0    = chunk_tab[2 * blk];
    int start = chunk_tab[2 * blk + 1];
    int seg = e0 >> 16, len = e0 & 0xffff;
    int b = seg >> 6;
    if (tid < 64) {
      int n = 0, fl = 0;
      if (tid < len) {
        int rec = perm[start + tid];
        n = (rec >> 8) & 0x1fff;
        fl = (n == 0 && (((rec >> 6) & 3) == 0)) ? 1 : 0;
      }
      n_s[tid] = n;
      flag_s[tid] = fl;
    }
    __syncthreads();
    {
      int p = tid >> 3, c = tid & 7;
      if (c < 6) {
        int n = n_s[p];
        float v;
        if (c < 3) v = x[((size_t)b * 3 + c) * NQ + n] - mean[seg * 3 + c];
        else       v = sn[((size_t)b * 3 + (c - 3)) * NQ + n];
        in_s[c][p] = v;
      }
    }
    /* stream L3 weights early (latency hides under L1+L2) */
    f16x8 af3[2][4];
    #pragma unroll
    for (int s = 0; s < 2; ++s)
      #pragma unroll
      for (int kb = 0; kb < 4; ++kb)
        af3[s][kb] = *(const f16x8*)(w2p + (size_t)(((wid * 2 + s) * 4 + kb) * 64 + lane) * 8);
    __syncthreads();

    /* L1 scalar 6->64 (weights from LDS, wave-uniform broadcast) */
    {
      float a0 = in_s[0][lane], a1 = in_s[1][lane], a2 = in_s[2][lane];
      float a3 = in_s[3][lane], a4 = in_s[4][lane], a5 = in_s[5][lane];
      f16x8 v;
      #pragma unroll
      for (int i = 0; i < 8; ++i) {
        const float* wr = &w0_s[(wid * 8 + i) * 6];
        float s = w0_s[384 + wid * 8 + i];
        s = fmaf(wr[0], a0, s); s = fmaf(wr[1], a1, s); s = fmaf(wr[2], a2, s);
        s = fmaf(wr[3], a3, s); s = fmaf(wr[4], a4, s); s = fmaf(wr[5], a5, s);
        v[i] = (f16)fmaxf(s, 0.f);
      }
      int kb = wid >> 2, q = wid & 3;
      *(f16x8*)&bufA[(g * KBA + kb) * ROWL + (pcol + 16 * q) * 8] = v;
    }
    __syncthreads();

    /* L2 MFMA 64->128 (A from held regs) */
    f32x4 acc1[4] = {};
    #pragma unroll
    for (int kb = 0; kb < 2; ++kb) {
      #pragma unroll
      for (int pt = 0; pt < 4; ++pt) {
        f16x8 bf = *(const f16x8*)&bufA[(pt * KBA + kb) * ROWL + lane * 8];
        acc1[pt] = __builtin_amdgcn_mfma_f32_16x16x32_f16(af2h[kb], bf, acc1[pt], 0, 0, 0);
      }
    }
    {
      float4 bb = *(const float4*)&b1v[wid * 16 + g * 4];
      int kbo = wid >> 1;
      int q   = ((wid & 1) << 1) + (g >> 1);
      int ee  = (g & 1) * 4;
      #pragma unroll
      for (int pt = 0; pt < 4; ++pt) {
        f16x4 v;
        v[0] = (f16)fmaxf(acc1[pt][0] + bb.x, 0.f);
        v[1] = (f16)fmaxf(acc1[pt][1] + bb.y, 0.f);
        v[2] = (f16)fmaxf(acc1[pt][2] + bb.z, 0.f);
        v[3] = (f16)fmaxf(acc1[pt][3] + bb.w, 0.f);
        *(f16x4*)&bufH1[(pt * 4 + kbo) * ROWL + (pcol + 16 * q) * 8 + ee] = v;
      }
    }
    __syncthreads();

    /* L3 MFMA 128->256 (A streamed this chunk) */
    f32x4 acc2[2][4] = {};
    #pragma unroll
    for (int kb = 0; kb < 4; ++kb) {
      #pragma unroll
      for (int pt = 0; pt < 4; ++pt) {
        f16x8 bf = *(const f16x8*)&bufH1[(pt * 4 + kb) * ROWL + lane * 8];
        acc2[0][pt] = __builtin_amdgcn_mfma_f32_16x16x32_f16(af3[0][kb], bf, acc2[0][pt], 0, 0, 0);
        acc2[1][pt] = __builtin_amdgcn_mfma_f32_16x16x32_f16(af3[1][kb], bf, acc2[1][pt], 0, 0, 0);
      }
    }
    {
      int kbo = 2 + wid;
      #pragma unroll
      for (int s = 0; s < 2; ++s) {
        float4 bb = *(const float4*)&b2v[(wid * 2 + s) * 16 + g * 4];
        int q  = 2 * s + (g >> 1);
        int ee = (g & 1) * 4;
        #pragma unroll
        for (int pt = 0; pt < 4; ++pt) {
          f16x4 v;
          v[0] = (f16)fmaxf(acc2[s][pt][0] + bb.x, 0.f);
          v[1] = (f16)fmaxf(acc2[s][pt][1] + bb.y, 0.f);
          v[2] = (f16)fmaxf(acc2[s][pt][2] + bb.z, 0.f);
          v[3] = (f16)fmaxf(acc2[s][pt][3] + bb.w, 0.f);
          *(f16x4*)&bufA[(pt * KBA + kbo) * ROWL + (pcol + 16 * q) * 8 + ee] = v;
        }
      }
    }
    __syncthreads();

    /* L4 MFMA 320->384 (A from held regs) */
    f32x4 acc3[3][4] = {};
    #pragma unroll
    for (int kb = 0; kb < KBA; ++kb) {
      #pragma unroll
      for (int pt = 0; pt < 4; ++pt) {
        f16x8 bf = *(const f16x8*)&bufA[(pt * KBA + kb) * ROWL + lane * 8];
        acc3[0][pt] = __builtin_amdgcn_mfma_f32_16x16x32_f16(af4h[0][kb], bf, acc3[0][pt], 0, 0, 0);
        acc3[1][pt] = __builtin_amdgcn_mfma_f32_16x16x32_f16(af4h[1][kb], bf, acc3[1][pt], 0, 0, 0);
        acc3[2][pt] = __builtin_amdgcn_mfma_f32_16x16x32_f16(af4h[2][kb], bf, acc3[2][pt], 0, 0, 0);
      }
    }
    /* epilogue: bias+relu, fallback, per-channel max over 64 points, one atomic */
    {
      int fl[4], vld[4];
      #pragma unroll
      for (int pt = 0; pt < 4; ++pt) {
        fl[pt]  = flag_s[pt * 16 + pcol];
        vld[pt] = (pt * 16 + pcol) < len;
      }
      #pragma unroll
      for (int c = 0; c < 3; ++c) {
        int ct = wid * 3 + c;
        #pragma unroll
        for (int j = 0; j < 4; ++j) {
          float bj = b3_s[ct * 16 + g * 4 + j];
          float vm = 0.f;
          #pragma unroll
          for (int pt = 0; pt < 4; ++pt) {
            float v = fmaxf(acc3[c][pt][j] + bj, 0.f);
            if (fl[pt]) fallback[b * 384 + ct * 16 + g * 4 + j] = v;
            if (!vld[pt]) v = 0.f;
            vm = fmaxf(vm, v);
          }
          vm = fmaxf(vm, __shfl_xor(vm, 1));
          vm = fmaxf(vm, __shfl_xor(vm, 2));
          vm = fmaxf(vm, __shfl_xor(vm, 4));
          vm = fmaxf(vm, __shfl_xor(vm, 8));
          if (pcol == 0)
            atomicMax((int*)&node_max[(size_t)seg * 384 + ct * 16 + g * 4 + j],
                      __float_as_int(vm));
        }
      }
    }
  }
}

/* ---------------- kernel Dg: gather + pack KNN input to B-fragments -------------------- */
__global__ __launch_bounds__(256) void kDg(
    const float* __restrict__ mean, const float* __restrict__ node_max,
    const float* __restrict__ fallback, const int* __restrict__ cnt,
    const int* __restrict__ knn_I, const float* __restrict__ centerb,
    f16* __restrict__ augP) {
  int idx = blockIdx.x * 256 + threadIdx.x;
  if (idx < NCOLS_D * 48) {
    int col = idx / 48;
    int rg  = idx - col * 48;
    int kk = col >> 9, seg = col & 511, b = seg >> 6;
    int nb = knn_I[seg * 9 + kk];
    const float* src = (cnt[b * 64 + nb] > 0) ? (node_max + (size_t)(b * 64 + nb) * 384)
                                              : (fallback + (size_t)b * 384);
    int r = rg * 8;
    f16x8 v;
    #pragma unroll
    for (int e = 0; e < 8; ++e) v[e] = (f16)src[r + e];
    int ct = col >> 4, pc = col & 15;
    int kb = r >> 5, ks = (r >> 3) & 3;
    *(f16x8*)&augP[(size_t)((ct * 13 + kb) * 64 + pc + 16 * ks) * 8] = v;
  } else if (idx < NCOLS_D * 48 + NCOLS_D) {
    int col = idx - NCOLS_D * 48;
    int kk = col >> 9, seg = col & 511, b = seg >> 6;
    int nb = knn_I[seg * 9 + kk];
    f16x8 v = {};
    #pragma unroll
    for (int c = 0; c < 3; ++c)
      v[c] = (f16)(mean[(b * 64 + nb) * 3 + c] - centerb[seg * 3 + c]);
    int ct = col >> 4, pc = col & 15;
    *(f16x8*)&augP[(size_t)((ct * 13 + 12) * 64 + pc) * 8] = v;
    f16x8 z = {};
    #pragma unroll
    for (int ks = 1; ks < 4; ++ks)
      *(f16x8*)&augP[(size_t)((ct * 13 + 12) * 64 + pc + 16 * ks) * 8] = z;
  }
}

/* ---------------- generic MFMA GEMM: C[64r x 64c]/block, 4 waves, no LDS ---------------- */
template<int NKB_IN, int NKB_OUT, int MODE>
__global__ __launch_bounds__(256) void kGemm(
    const f16* __restrict__ Ap, const f16* __restrict__ Bp,
    const float* __restrict__ bias, f16* __restrict__ outP, float* __restrict__ outF) {
  int cb = blockIdx.x;
  int rb = blockIdx.y;
  int tid = threadIdx.x;
  int wid = __builtin_amdgcn_readfirstlane(tid >> 6);
  int lane = tid & 63;
  int rt = rb * 4 + wid;
  f32x4 acc[4] = {};
  const f16* ap = Ap + (size_t)rt * NKB_IN * 512;
  const f16* bp = Bp + (size_t)cb * 4 * NKB_IN * 512;
  #pragma unroll
  for (int kb = 0; kb < NKB_IN; ++kb) {
    f16x8 af = *(const f16x8*)(ap + (size_t)(kb * 64 + lane) * 8);
    #pragma unroll
    for (int ct = 0; ct < 4; ++ct) {
      f16x8 bf = *(const f16x8*)(bp + (size_t)((ct * NKB_IN + kb) * 64 + lane) * 8);
      acc[ct] = __builtin_amdgcn_mfma_f32_16x16x32_f16(af, bf, acc[ct], 0, 0, 0);
    }
  }
  int pcol = lane & 15, g = lane >> 4;
  float4 bb = *(const float4*)&bias[rt * 16 + g * 4];
  float bj[4] = {bb.x, bb.y, bb.z, bb.w};
  if (MODE == 0) {
    int k0 = rt * 16 + g * 4;
    int kb2 = k0 >> 5, ks2 = (k0 >> 3) & 3, ee = k0 & 7;
    #pragma unroll
    for (int ct = 0; ct < 4; ++ct) {
      f16x4 v;
      #pragma unroll
      for (int j = 0; j < 4; ++j) v[j] = (f16)fmaxf(acc[ct][j] + bj[j], 0.f);
      int ctc = cb * 4 + ct;
      *(f16x4*)&outP[(size_t)((ctc * NKB_OUT + kb2) * 64 + pcol + 16 * ks2) * 8 + ee] = v;
    }
  } else if (MODE == 1) {
    #pragma unroll
    for (int ct = 0; ct < 4; ++ct) {
      f16x4 v;
      #pragma unroll
      for (int j = 0; j < 4; ++j) v[j] = (f16)fmaxf(acc[ct][j] + bj[j], 0.f);
      int col = cb * 64 + ct * 16 + pcol;
      *(f16x4*)&outP[(size_t)col * 512 + rt * 16 + g * 4] = v;
    }
  } else {
    #pragma unroll
    for (int j = 0; j < 4; ++j) {
      float v = fmaxf(acc[0][j] + bj[j], 0.f);
      #pragma unroll
      for (int ct = 1; ct < 4; ++ct) v = fmaxf(v, fmaxf(acc[ct][j] + bj[j], 0.f));
      v = fmaxf(v, __shfl_xor(v, 1));
      v = fmaxf(v, __shfl_xor(v, 2));
      v = fmaxf(v, __shfl_xor(v, 4));
      v = fmaxf(v, __shfl_xor(v, 8));
      if (pcol == 0) outF[cb * 1024 + rt * 16 + g * 4 + j] = v;
    }
  }
}

/* ---------------- kernel Dmax: max over 9 kk -> kE input pack --------------------------- */
__global__ __launch_bounds__(256) void kDmax(const f16* __restrict__ gbuf,
                                             const float* __restrict__ centerb,
                                             f16* __restrict__ keinP) {
  int idx = blockIdx.x * 256 + threadIdx.x;
  if (idx < SEGS * 64) {
    int seg = idx >> 6;
    int rg  = idx & 63;
    int r = rg * 8;
    float m[8] = {};
    for (int kk = 0; kk < 9; ++kk) {
      f16x8 gv = *(const f16x8*)&gbuf[(size_t)(kk * 512 + seg) * 512 + r];
      #pragma unroll
      for (int e = 0; e < 8; ++e) m[e] = fmaxf(m[e], (float)gv[e]);
    }
    f16x8 v;
    #pragma unroll
    for (int e = 0; e < 8; ++e) v[e] = (f16)m[e];
    int ct = seg >> 4, pc = seg & 15;
    int kb = r >> 5, ks = (r >> 3) & 3;
    *(f16x8*)&keinP[(size_t)((ct * 17 + kb) * 64 + pc + 16 * ks) * 8] = v;
  } else if (idx < SEGS * 64 + SEGS) {
    int seg = idx - SEGS * 64;
    f16x8 v = {};
    #pragma unroll
    for (int c = 0; c < 3; ++c) v[c] = (f16)centerb[seg * 3 + c];
    int ct = seg >> 4, pc = seg & 15;
    *(f16x8*)&keinP[(size_t)((ct * 17 + 16) * 64 + pc) * 8] = v;
    f16x8 z = {};
    #pragma unroll
    for (int ks = 1; ks < 4; ++ks)
      *(f16x8*)&keinP[(size_t)((ct * 17 + 16) * 64 + pc + 16 * ks) * 8] = z;
  }
}

/* ---------------- launcher -------------------------------------------------------------- */
extern "C" void kernel_launch(void* const* d_in, const int* in_sizes, int n_in,
                              void* d_out, int out_size, void* d_ws, size_t ws_size,
                              hipStream_t stream) {
  const float* x      = (const float*)d_in[0];
  const float* sn     = (const float*)d_in[1];
  const float* node   = (const float*)d_in[2];
  const int*   knn_I  = (const int*)d_in[3];
  const float* pr_w0  = (const float*)d_in[4];
  const float* pr_b0  = (const float*)d_in[5];
  const float* pr_w1  = (const float*)d_in[6];
  const float* pr_b1  = (const float*)d_in[7];
  const float* pr_w2  = (const float*)d_in[8];
  const float* pr_b2  = (const float*)d_in[9];
  const float* pr_w3  = (const float*)d_in[10];
  const float* pr_b3  = (const float*)d_in[11];
  const float* knn_w0 = (const float*)d_in[12];
  const float* knn_b0 = (const float*)d_in[13];
  const float* knn_w1 = (const float*)d_in[14];
  const float* knn_b1 = (const float*)d_in[15];
  const float* fin_w0 = (const float*)d_in[16];
  const float* fin_b0 = (const float*)d_in[17];
  const float* fin_w1 = (const float*)d_in[18];
  const float* fin_b1 = (const float*)d_in[19];
  float* out = (float*)d_out;
  char* ws = (char*)d_ws;

  int*   idx_buf   = (int*)(ws + OFF_IDX);
  int*   perm      = (int*)(ws + OFF_PERM);
  int*   cnt       = (int*)(ws + OFF_CNT);
  float* sums      = (float*)(ws + OFF_SUMS);
  int*   offs      = (int*)(ws + OFF_OFFS);
  int*   cursor    = (int*)(ws + OFF_CURSOR);
  int*   nchunks   = (int*)(ws + OFF_NCHUNK);
  int*   chunk_tab = (int*)(ws + OFF_CHUNKTAB);
  float* mean      = (float*)(ws + OFF_MEAN);
  float* fallback  = (float*)(ws + OFF_FALLBACK);
  float* node_max  = (float*)(ws + OFF_NODEMAX);
  float* centerb   = (float*)(ws + OFF_CENTER);
  f16*   w1p       = (f16*)(ws + OFF_W1P);
  f16*   w2p       = (f16*)(ws + OFF_W2P);
  f16*   w3p       = (f16*)(ws + OFF_W3P);
  f16*   knw0p     = (f16*)(ws + OFF_KNW0P);
  f16*   knw1p     = (f16*)(ws + OFF_KNW1P);
  f16*   finw0p    = (f16*)(ws + OFF_FINW0P);
  f16*   finw1p    = (f16*)(ws + OFF_FINW1P);
  f16*   augP      = (f16*)(ws + OFF_AUG);
  f16*   mid1P     = (f16*)(ws + OFF_MID1);
  f16*   gbuf      = (f16*)(ws + OFF_GBUF);
  f16*   keinP     = (f16*)(ws + OFF_KEIN);
  f16*   midEP     = (f16*)(ws + OFF_MIDE);

  hipMemsetAsync(ws + OFF_CNT, 0, 8192, stream);                 /* cnt + sums */
  hipMemsetAsync(ws + OFF_NODEMAX, 0, (size_t)SEGS * 384 * 4, stream);

  kW<<<7200, 256, 0, stream>>>(pr_w1, pr_w2, pr_w3, knn_w0, knn_w1, fin_w0, fin_w1,
                               w1p, w2p, w3p, knw0p, knw1p, finw0p, finw1p);

  dim3 gA(NQ / 256, BQ);
  kA<<<gA, 256, 0, stream>>>(x, node, idx_buf, cnt, sums);
  kB<<<1, 256, 0, stream>>>(cnt, sums, offs, cursor, nchunks, chunk_tab, mean, knn_I, centerb);
  kA2<<<gA, 256, 0, stream>>>(idx_buf, cursor, perm);
  kC<<<256, 512, 0, stream>>>(x, sn, mean, perm, chunk_tab, nchunks,
                              pr_w0, pr_b0, w1p, pr_b1, w2p, pr_b2, w3p, pr_b3,
                              node_max, fallback);
  kDg<<<(NCOLS_D * 48 + NCOLS_D + 255) / 256, 256, 0, stream>>>(
      mean, node_max, fallback, cnt, knn_I, centerb, augP);
  kGemm<13, 16, 0><<<dim3(72, 8), 256, 0, stream>>>(knw0p, augP, knn_b0, mid1P, nullptr);
  kGemm<16, 0, 1><<<dim3(72, 8), 256, 0, stream>>>(knw1p, mid1P, knn_b1, gbuf, nullptr);
  kDmax<<<(SEGS * 64 + SEGS + 255) / 256, 256, 0, stream>>>(gbuf, centerb, keinP);
  kGemm<17, 24, 0><<<dim3(8, 12), 256, 0, stream>>>(finw0p, keinP, fin_b0, midEP, nullptr);
  kGemm<24, 0, 2><<<dim3(8, 16), 256, 0, stream>>>(finw1p, midEP, fin_b1, nullptr, out);
}